// Round 3
// baseline (1848.891 us; speedup 1.0000x reference)
//
#include <hip/hip_runtime.h>
#include <hip/hip_bf16.h>

#define B 64
#define N0 2048
#define DEG 16
#define IN_DIM 128
#define H 30
#define NH 11
#define K1 1844
#define K2 1660
#define K3 1494
#define NTOT (B * N0)        /* 131072 */
#define ETOT (NTOT * DEG)    /* 2097152 */
#define EPG (ETOT / B)       /* 32768 edges per graph, contiguous */
#define RSTRIDE 32           /* padded row stride for r (aligned 32B gathers) */

// ---------------------------------------------------------------------------
// Prep: fold layernorm gamma into layer-1 weights; combine rel/root weights
// into [K][60] blocks so the proj kernels read one contiguous uniform row.
// ---------------------------------------------------------------------------
__global__ __launch_bounds__(256) void k_prep(
    const float* __restrict__ ln_g, const float* __restrict__ ln_b,
    const float* __restrict__ Wrel1, const float* __restrict__ brel1, const float* __restrict__ Wroot1,
    const float* __restrict__ Wrel2, const float* __restrict__ Wroot2,
    const float* __restrict__ Wrel3, const float* __restrict__ Wroot3,
    float* __restrict__ Wc1, float* __restrict__ S1, float* __restrict__ T1,
    float* __restrict__ Wc2, float* __restrict__ Wc3)
{
    int tid = threadIdx.x;
    for (int i = tid; i < IN_DIM * 60; i += 256) {
        int j = i / 60, c = i - j * 60;
        float w = (c < H) ? Wrel1[j * H + c] : Wroot1[j * H + (c - H)];
        Wc1[i] = w * ln_g[j];
    }
    if (tid < 60) {
        int c = tid;
        float s = 0.f, tt = 0.f;
        for (int j = 0; j < IN_DIM; ++j) {
            float w = (c < H) ? Wrel1[j * H + c] : Wroot1[j * H + (c - H)];
            s += w * ln_g[j];
            tt += w * ln_b[j];
        }
        S1[c] = s;
        T1[c] = (c < H) ? tt : tt + brel1[c - H];
    }
    for (int i = tid; i < H * 60; i += 256) {
        int j = i / 60, c = i - j * 60;
        Wc2[i] = (c < H) ? Wrel2[j * H + c] : Wroot2[j * H + (c - H)];
        Wc3[i] = (c < H) ? Wrel3[j * H + c] : Wroot3[j * H + (c - H)];
    }
}

// ---------------------------------------------------------------------------
// Layer 1: fused LayerNorm + dual projection. Thread-per-row, single pass.
// r written at stride 32 (padded, cols 30/31 zeroed) for aligned agg gathers.
// ---------------------------------------------------------------------------
__global__ __launch_bounds__(256) void k_lnproj(
    const float* __restrict__ x, const float* __restrict__ Wc,
    const float* __restrict__ S, const float* __restrict__ T,
    float* __restrict__ r, float* __restrict__ t)
{
    int row = blockIdx.x * 256 + threadIdx.x;
    const float* xr = x + (size_t)row * IN_DIM;
    float acc[60];
#pragma unroll
    for (int c = 0; c < 60; ++c) acc[c] = 0.f;
    float sum = 0.f, sumsq = 0.f;
    for (int jb = 0; jb < IN_DIM; jb += 8) {
        float4 a0 = *(const float4*)(xr + jb);
        float4 a1 = *(const float4*)(xr + jb + 4);
        float xs[8] = {a0.x, a0.y, a0.z, a0.w, a1.x, a1.y, a1.z, a1.w};
#pragma unroll
        for (int u = 0; u < 8; ++u) {
            float xv = xs[u];
            sum += xv;
            sumsq += xv * xv;
            const float* wrow = Wc + (jb + u) * 60;
#pragma unroll
            for (int c = 0; c < 60; ++c) acc[c] += xv * wrow[c];
        }
    }
    float mean = sum * (1.f / 128.f);
    float var = sumsq * (1.f / 128.f) - mean * mean;
    float rstd = 1.0f / sqrtf(var + 1e-5f);
    int rb = row * RSTRIDE, tb = row * H;
#pragma unroll
    for (int c = 0; c < H; ++c)
        r[rb + c] = rstd * (acc[c] - mean * S[c]) + T[c];
    r[rb + 30] = 0.f; r[rb + 31] = 0.f;
#pragma unroll
    for (int c = 0; c < H; ++c)
        t[tb + c] = rstd * (acc[30 + c] - mean * S[30 + c]) + T[30 + c];
}

// ---------------------------------------------------------------------------
// Layers 2/3 projection: r = h@Wrel (stride 32), t = h@Wroot + brel
// ---------------------------------------------------------------------------
__global__ __launch_bounds__(256) void k_proj30(
    const float* __restrict__ h, const float* __restrict__ Wc,
    const float* __restrict__ brel, float* __restrict__ r, float* __restrict__ t)
{
    int row = blockIdx.x * 256 + threadIdx.x;
    const float* hr = h + (size_t)row * H;
    float hv[H];
#pragma unroll
    for (int j = 0; j < H; j += 2) {
        float2 v = *(const float2*)(hr + j);
        hv[j] = v.x; hv[j + 1] = v.y;
    }
    float acc[60];
#pragma unroll
    for (int c = 0; c < H; ++c) acc[c] = 0.f;
#pragma unroll
    for (int c = 0; c < H; ++c) acc[30 + c] = brel[c];
    for (int j = 0; j < H; ++j) {
        const float* wrow = Wc + j * 60;
        float xv = hv[j];
#pragma unroll
        for (int c = 0; c < 60; ++c) acc[c] += xv * wrow[c];
    }
    int rb = row * RSTRIDE, tb = row * H;
#pragma unroll
    for (int c = 0; c < H; ++c) { r[rb + c] = acc[c]; t[tb + c] = acc[30 + c]; }
    r[rb + 30] = 0.f; r[rb + 31] = 0.f;
}

// ---------------------------------------------------------------------------
// Edge aggregation in LDS. Workgroup = (graph g, feature-group fg of 8).
// 8 lanes per edge: lane j reads r[src*32+f0+j] -- one contiguous 32B chunk
// per edge (8 transactions/wave instead of ~128). Branchless: dropped edges
// (ew==0) add 0 to acc[0][*] (dst clamped). LDS acc[node][8]: group lanes hit
// 8 distinct banks. Fused +t, relu on write-out.
// ---------------------------------------------------------------------------
__global__ __launch_bounds__(1024) void k_agg_lds(
    const int* __restrict__ src, const int* __restrict__ dst,
    const float* __restrict__ ew, const float* __restrict__ rp,
    const float* __restrict__ t, float* __restrict__ h, int n)
{
    __shared__ float acc[2048 * 8];
    int g = blockIdx.x >> 2;
    int fg = blockIdx.x & 3;
    int f0 = fg * 8;                       // fg==3: cols 24..31 (30/31 zero pads)
    int nwr = (fg == 3) ? 6 : 8;
    int nodebase = g * n;
    for (int i = threadIdx.x; i < 2048 * 8; i += 1024) acc[i] = 0.f;
    __syncthreads();
    int gid = threadIdx.x >> 3;            // 128 groups of 8 lanes
    int lane = threadIdx.x & 7;
    int ebase = g * EPG;
#pragma unroll 8
    for (int i = 0; i < EPG / 128; ++i) {
        int e = ebase + i * 128 + gid;
        float w = ew[e];
        int s = src[e];
        int d = dst[e] - nodebase;
        d = (d < 0) ? 0 : d;               // dropped edges: dst==0, w==0 -> adds 0
        float v = rp[(size_t)s * RSTRIDE + f0 + lane] * w;
        unsafeAtomicAdd(&acc[d * 8 + lane], v);
    }
    __syncthreads();
    for (int i = threadIdx.x; i < n * 8; i += 1024) {
        int node = i >> 3, f = i & 7;
        if (f < nwr) {
            int gi = (nodebase + node) * H + f0 + f;
            h[gi] = fmaxf(acc[i] + t[gi], 0.f);
        }
    }
}

// score = tanh((h @ w) / ||w||)
__global__ __launch_bounds__(256) void k_score(
    const float* __restrict__ h, const float* __restrict__ w, float* __restrict__ score)
{
    int row = blockIdx.x * 256 + threadIdx.x;
    const float* hr = h + (size_t)row * H;
    float nw = 0.f, d = 0.f;
#pragma unroll
    for (int j = 0; j < H; ++j) {
        float wv = w[j];
        nw += wv * wv;
        d += hr[j] * wv;
    }
    score[row] = tanhf(d / sqrtf(nw));
}

// ---------------------------------------------------------------------------
// Per-graph top-k: bitonic sort of 2048 packed keys (desc score, asc idx) in
// LDS -- matches jax.lax.top_k total order incl. tie-break by lower index.
// ---------------------------------------------------------------------------
__global__ __launch_bounds__(256) void k_topk(
    const float* __restrict__ score, const float* __restrict__ h,
    float* __restrict__ xout, int* __restrict__ newidx, int n, int k)
{
    __shared__ unsigned long long keys[2048];
    int g = blockIdx.x;
    for (int i = threadIdx.x; i < 2048; i += 256) {
        unsigned long long key = ~0ull;
        if (i < n) {
            float s = score[g * n + i];
            if (s == 0.f) s = 0.f;                 // canonicalize -0 -> +0
            unsigned u = __float_as_uint(s);
            unsigned asc = (u & 0x80000000u) ? ~u : (u | 0x80000000u);
            unsigned desc = ~asc;                  // ascending key = descending score
            key = ((unsigned long long)desc << 32) | (unsigned)i;
        }
        keys[i] = key;
    }
    __syncthreads();
    for (int kk = 2; kk <= 2048; kk <<= 1) {
        for (int jj = kk >> 1; jj > 0; jj >>= 1) {
            for (int i = threadIdx.x; i < 2048; i += 256) {
                int ixj = i ^ jj;
                if (ixj > i) {
                    unsigned long long a = keys[i], b = keys[ixj];
                    bool up = ((i & kk) == 0);
                    if ((a > b) == up) { keys[i] = b; keys[ixj] = a; }
                }
            }
            __syncthreads();
        }
    }
    for (int i = threadIdx.x; i < n; i += 256) newidx[g * n + i] = -1;
    __syncthreads();
    for (int j = threadIdx.x; j < k; j += 256) {
        int idx = (int)(keys[j] & 0xffffffffu);
        newidx[g * n + idx] = j;
    }
    for (int m = threadIdx.x; m < k * H; m += 256) {
        int j = m / H, f = m - j * H;
        int idx = (int)(keys[j] & 0xffffffffu);
        float val = score[g * n + idx];
        xout[(g * k + j) * H + f] = h[(g * n + idx) * H + f] * val;
    }
}

// Edge remap after pooling (element-wise; safe in place).
__global__ void k_remap(const int* __restrict__ srcIn, const int* __restrict__ dstIn,
                        const float* __restrict__ ewIn, const int* __restrict__ newidx,
                        int* __restrict__ srcOut, int* __restrict__ dstOut,
                        float* __restrict__ ewOut, int nOld, int kNew)
{
    int e = blockIdx.x * 256 + threadIdx.x;
    int s = srcIn[e], d = dstIn[e];
    float w = ewIn[e];
    int g = s / nOld;
    int ns = newidx[g * nOld + (s - g * nOld)];
    int nd = newidx[g * nOld + (d % nOld)];
    bool keep = (ns >= 0) && (nd >= 0);
    srcOut[e] = keep ? g * kNew + ns : 0;
    dstOut[e] = keep ? g * kNew + nd : 0;
    ewOut[e] = keep ? w : 0.f;
}

// Per-graph readout: [max ; mean] over k rows -> out[g][0..59]
__global__ __launch_bounds__(256) void k_readout(
    const float* __restrict__ x, float* __restrict__ out, int k)
{
    __shared__ float smax[8][32], ssum[8][32];
    int g = blockIdx.x;
    int f = threadIdx.x & 31, rr = threadIdx.x >> 5;
    float mx = -INFINITY, sm = 0.f;
    if (f < H) {
        for (int row = rr; row < k; row += 8) {
            float v = x[(g * k + row) * H + f];
            mx = fmaxf(mx, v);
            sm += v;
        }
    }
    smax[rr][f] = mx; ssum[rr][f] = sm;
    __syncthreads();
    if (rr == 0 && f < H) {
        for (int q = 1; q < 8; ++q) { mx = fmaxf(mx, smax[q][f]); sm += ssum[q][f]; }
        out[g * 60 + f] = mx;
        out[g * 60 + 30 + f] = sm / (float)k;
    }
}

__global__ void k_z(const float* __restrict__ x1, const float* __restrict__ x2,
                    const float* __restrict__ x3, float* __restrict__ z)
{
    int i = blockIdx.x * 256 + threadIdx.x;
    z[i] = fmaxf(x1[i] + x2[i] + x3[i], 0.f);
}

// a1[h,b,o] = relu(sum_d z[b,d]*W1[h,d,o] + b1[h,o]),  o<240, d<60
__global__ __launch_bounds__(256) void k_mlp1(
    const float* __restrict__ z, const float* __restrict__ W,
    const float* __restrict__ bias, float* __restrict__ a)
{
    int hb = blockIdx.x, hh = hb >> 6, b = hb & 63;
    __shared__ float zr[60];
    if (threadIdx.x < 60) zr[threadIdx.x] = z[b * 60 + threadIdx.x];
    __syncthreads();
    int o = threadIdx.x;
    if (o < 240) {
        float acc = bias[hh * 240 + o];
        const float* Wp = W + hh * 60 * 240;
#pragma unroll
        for (int d = 0; d < 60; ++d) acc += zr[d] * Wp[d * 240 + o];
        a[(hh * B + b) * 240 + o] = fmaxf(acc, 0.f);
    }
}

// a2[h,b,p] = relu(sum_o a1[h,b,o]*W2[h,o,p] + b2[h,p]),  p<960, o<240
__global__ __launch_bounds__(256) void k_mlp2(
    const float* __restrict__ a1, const float* __restrict__ W,
    const float* __restrict__ bias, float* __restrict__ a2)
{
    int hb = blockIdx.x, hh = hb >> 6, b = hb & 63;
    __shared__ float ar[240];
    if (threadIdx.x < 240) ar[threadIdx.x] = a1[(hh * B + b) * 240 + threadIdx.x];
    __syncthreads();
    const float* Wp = W + hh * 240 * 960;
    for (int p = threadIdx.x; p < 960; p += 256) {
        float acc = bias[hh * 960 + p];
        for (int o = 0; o < 240; ++o) acc += ar[o] * Wp[o * 960 + p];
        a2[(hh * B + b) * 960 + p] = fmaxf(acc, 0.f);
    }
}

// out[h,b,q] = sum_p a2[h,b,p]*W3[h,p,q] + b3[h,q],  q<8, p<960
__global__ __launch_bounds__(64) void k_mlp3(
    const float* __restrict__ a2, const float* __restrict__ W,
    const float* __restrict__ bias, float* __restrict__ out)
{
    int hb = blockIdx.x, hh = hb >> 6, b = hb & 63;
    __shared__ float ar[960];
    __shared__ float part[64];
    for (int i = threadIdx.x; i < 960; i += 64) ar[i] = a2[(hh * B + b) * 960 + i];
    __syncthreads();
    int q = threadIdx.x & 7, c = threadIdx.x >> 3;
    const float* Wp = W + hh * 960 * 8;
    float acc = 0.f;
    for (int p = c; p < 960; p += 8) acc += ar[p] * Wp[p * 8 + q];
    part[threadIdx.x] = acc;
    __syncthreads();
    if (threadIdx.x < 8) {
        float s = bias[hh * 8 + threadIdx.x];
        for (int cc = 0; cc < 8; ++cc) s += part[cc * 8 + threadIdx.x];
        out[(hh * B + b) * 8 + threadIdx.x] = s;
    }
}

// ---------------------------------------------------------------------------
extern "C" void kernel_launch(void* const* d_in, const int* in_sizes, int n_in,
                              void* d_out, int out_size, void* d_ws, size_t ws_size,
                              hipStream_t stream)
{
    const float* x       = (const float*)d_in[0];
    const int*   eidx    = (const int*)d_in[1];
    const int*   src0    = eidx;
    const int*   dst0    = eidx + ETOT;
    const float* ew0     = (const float*)d_in[2];
    const float* ln_g    = (const float*)d_in[4];
    const float* ln_b    = (const float*)d_in[5];
    const float* W_rel1  = (const float*)d_in[6];
    const float* b_rel1  = (const float*)d_in[7];
    const float* W_root1 = (const float*)d_in[8];
    const float* W_rel2  = (const float*)d_in[9];
    const float* b_rel2  = (const float*)d_in[10];
    const float* W_root2 = (const float*)d_in[11];
    const float* W_rel3  = (const float*)d_in[12];
    const float* b_rel3  = (const float*)d_in[13];
    const float* W_root3 = (const float*)d_in[14];
    const float* pool_w1 = (const float*)d_in[15];
    const float* pool_w2 = (const float*)d_in[16];
    const float* pool_w3 = (const float*)d_in[17];
    const float* head_W1 = (const float*)d_in[18];
    const float* head_b1 = (const float*)d_in[19];
    const float* head_W2 = (const float*)d_in[20];
    const float* head_b2 = (const float*)d_in[21];
    const float* head_W3 = (const float*)d_in[22];
    const float* head_b3 = (const float*)d_in[23];

    // workspace carve (~90.4 MB)
    float* ws     = (float*)d_ws;
    float* rbuf   = ws;                              // NTOT*32 (padded)
    float* tbuf   = rbuf + (size_t)NTOT * RSTRIDE;   // NTOT*30
    float* abuf   = tbuf + (size_t)NTOT * H;         // NTOT*30 (h)
    float* xp     = abuf + (size_t)NTOT * H;         // NTOT*30 (pooled x)
    float* score  = xp + (size_t)NTOT * H;           // NTOT
    int*   newidx = (int*)(score + NTOT);            // NTOT
    int*   srcw   = newidx + NTOT;                   // ETOT
    int*   dstw   = srcw + ETOT;                     // ETOT
    float* eww    = (float*)(dstw + ETOT);           // ETOT
    float* x1     = eww + ETOT;                      // B*60
    float* x2     = x1 + B * 60;
    float* x3     = x2 + B * 60;
    float* zb     = x3 + B * 60;
    float* Wc1    = zb + B * 60;                     // 128*60
    float* S1     = Wc1 + IN_DIM * 60;               // 60
    float* T1     = S1 + 60;                         // 60
    float* Wc2    = T1 + 60;                         // 30*60
    float* Wc3    = Wc2 + H * 60;                    // 30*60
    float* a1     = rbuf;                            // alias: heads run after layers
    float* a2     = a1 + NH * B * 240;               // 11*64*960

    const int N2 = B * K1;   // 118016 = 461*256
    const int N3 = B * K2;   // 106240 = 415*256

    k_prep<<<1, 256, 0, stream>>>(ln_g, ln_b, W_rel1, b_rel1, W_root1,
                                  W_rel2, W_root2, W_rel3, W_root3,
                                  Wc1, S1, T1, Wc2, Wc3);

    // ---- layer 1 ----
    k_lnproj<<<NTOT / 256, 256, 0, stream>>>(x, Wc1, S1, T1, rbuf, tbuf);
    k_agg_lds<<<B * 4, 1024, 0, stream>>>(src0, dst0, ew0, rbuf, tbuf, abuf, N0);
    k_score<<<NTOT / 256, 256, 0, stream>>>(abuf, pool_w1, score);
    k_topk<<<B, 256, 0, stream>>>(score, abuf, xp, newidx, N0, K1);
    k_remap<<<ETOT / 256, 256, 0, stream>>>(src0, dst0, ew0, newidx, srcw, dstw, eww, N0, K1);
    k_readout<<<B, 256, 0, stream>>>(xp, x1, K1);

    // ---- layer 2 ----
    k_proj30<<<N2 / 256, 256, 0, stream>>>(xp, Wc2, b_rel2, rbuf, tbuf);
    k_agg_lds<<<B * 4, 1024, 0, stream>>>(srcw, dstw, eww, rbuf, tbuf, abuf, K1);
    k_score<<<N2 / 256, 256, 0, stream>>>(abuf, pool_w2, score);
    k_topk<<<B, 256, 0, stream>>>(score, abuf, xp, newidx, K1, K2);
    k_remap<<<ETOT / 256, 256, 0, stream>>>(srcw, dstw, eww, newidx, srcw, dstw, eww, K1, K2);
    k_readout<<<B, 256, 0, stream>>>(xp, x2, K2);

    // ---- layer 3 ----
    k_proj30<<<N3 / 256, 256, 0, stream>>>(xp, Wc3, b_rel3, rbuf, tbuf);
    k_agg_lds<<<B * 4, 1024, 0, stream>>>(srcw, dstw, eww, rbuf, tbuf, abuf, K2);
    k_score<<<N3 / 256, 256, 0, stream>>>(abuf, pool_w3, score);
    k_topk<<<B, 256, 0, stream>>>(score, abuf, xp, newidx, K2, K3);
    k_readout<<<B, 256, 0, stream>>>(xp, x3, K3);

    // ---- heads ----
    k_z<<<B * 60 / 256, 256, 0, stream>>>(x1, x2, x3, zb);
    k_mlp1<<<NH * B, 256, 0, stream>>>(zb, head_W1, head_b1, a1);
    k_mlp2<<<NH * B, 256, 0, stream>>>(a1, head_W2, head_b2, a2);
    k_mlp3<<<NH * B, 64, 0, stream>>>(a2, head_W3, head_b3, (float*)d_out);
}

// Round 4
// 1689.487 us; speedup vs baseline: 1.0944x; 1.0944x over previous
//
#include <hip/hip_runtime.h>
#include <hip/hip_bf16.h>

#define B 64
#define N0 2048
#define DEG 16
#define IN_DIM 128
#define H 30
#define NH 11
#define K1 1844
#define K2 1660
#define K3 1494
#define NTOT (B * N0)        /* 131072 */
#define ETOT (NTOT * DEG)    /* 2097152 */
#define EPG (ETOT / B)       /* 32768 edges per graph, contiguous */
#define RSTRIDE 32           /* padded row stride for r (aligned 32B gathers) */

// ---------------------------------------------------------------------------
// Prep: fold layernorm gamma into layer-1 weights; combine rel/root weights.
// ---------------------------------------------------------------------------
__global__ __launch_bounds__(256) void k_prep(
    const float* __restrict__ ln_g, const float* __restrict__ ln_b,
    const float* __restrict__ Wrel1, const float* __restrict__ brel1, const float* __restrict__ Wroot1,
    const float* __restrict__ Wrel2, const float* __restrict__ Wroot2,
    const float* __restrict__ Wrel3, const float* __restrict__ Wroot3,
    float* __restrict__ Wc1, float* __restrict__ S1, float* __restrict__ T1,
    float* __restrict__ Wc2, float* __restrict__ Wc3)
{
    int tid = threadIdx.x;
    for (int i = tid; i < IN_DIM * 60; i += 256) {
        int j = i / 60, c = i - j * 60;
        float w = (c < H) ? Wrel1[j * H + c] : Wroot1[j * H + (c - H)];
        Wc1[i] = w * ln_g[j];
    }
    if (tid < 60) {
        int c = tid;
        float s = 0.f, tt = 0.f;
        for (int j = 0; j < IN_DIM; ++j) {
            float w = (c < H) ? Wrel1[j * H + c] : Wroot1[j * H + (c - H)];
            s += w * ln_g[j];
            tt += w * ln_b[j];
        }
        S1[c] = s;
        T1[c] = (c < H) ? tt : tt + brel1[c - H];
    }
    for (int i = tid; i < H * 60; i += 256) {
        int j = i / 60, c = i - j * 60;
        Wc2[i] = (c < H) ? Wrel2[j * H + c] : Wroot2[j * H + (c - H)];
        Wc3[i] = (c < H) ? Wrel3[j * H + c] : Wroot3[j * H + (c - H)];
    }
}

// ---------------------------------------------------------------------------
// Layer 1: fused LayerNorm + dual projection. Thread-per-row, single pass.
// ---------------------------------------------------------------------------
__global__ __launch_bounds__(256) void k_lnproj(
    const float* __restrict__ x, const float* __restrict__ Wc,
    const float* __restrict__ S, const float* __restrict__ T,
    float* __restrict__ r, float* __restrict__ t)
{
    int row = blockIdx.x * 256 + threadIdx.x;
    const float* xr = x + (size_t)row * IN_DIM;
    float acc[60];
#pragma unroll
    for (int c = 0; c < 60; ++c) acc[c] = 0.f;
    float sum = 0.f, sumsq = 0.f;
    for (int jb = 0; jb < IN_DIM; jb += 8) {
        float4 a0 = *(const float4*)(xr + jb);
        float4 a1 = *(const float4*)(xr + jb + 4);
        float xs[8] = {a0.x, a0.y, a0.z, a0.w, a1.x, a1.y, a1.z, a1.w};
#pragma unroll
        for (int u = 0; u < 8; ++u) {
            float xv = xs[u];
            sum += xv;
            sumsq += xv * xv;
            const float* wrow = Wc + (jb + u) * 60;
#pragma unroll
            for (int c = 0; c < 60; ++c) acc[c] += xv * wrow[c];
        }
    }
    float mean = sum * (1.f / 128.f);
    float var = sumsq * (1.f / 128.f) - mean * mean;
    float rstd = 1.0f / sqrtf(var + 1e-5f);
    int rb = row * RSTRIDE, tb = row * H;
#pragma unroll
    for (int c = 0; c < H; ++c)
        r[rb + c] = rstd * (acc[c] - mean * S[c]) + T[c];
    r[rb + 30] = 0.f; r[rb + 31] = 0.f;
#pragma unroll
    for (int c = 0; c < H; ++c)
        t[tb + c] = rstd * (acc[30 + c] - mean * S[30 + c]) + T[30 + c];
}

// ---------------------------------------------------------------------------
// Layers 2/3 projection: r = h@Wrel (stride 32), t = h@Wroot + brel
// ---------------------------------------------------------------------------
__global__ __launch_bounds__(256) void k_proj30(
    const float* __restrict__ h, const float* __restrict__ Wc,
    const float* __restrict__ brel, float* __restrict__ r, float* __restrict__ t)
{
    int row = blockIdx.x * 256 + threadIdx.x;
    const float* hr = h + (size_t)row * H;
    float hv[H];
#pragma unroll
    for (int j = 0; j < H; j += 2) {
        float2 v = *(const float2*)(hr + j);
        hv[j] = v.x; hv[j + 1] = v.y;
    }
    float acc[60];
#pragma unroll
    for (int c = 0; c < H; ++c) acc[c] = 0.f;
#pragma unroll
    for (int c = 0; c < H; ++c) acc[30 + c] = brel[c];
    for (int j = 0; j < H; ++j) {
        const float* wrow = Wc + j * 60;
        float xv = hv[j];
#pragma unroll
        for (int c = 0; c < 60; ++c) acc[c] += xv * wrow[c];
    }
    int rb = row * RSTRIDE, tb = row * H;
#pragma unroll
    for (int c = 0; c < H; ++c) { r[rb + c] = acc[c]; t[tb + c] = acc[30 + c]; }
    r[rb + 30] = 0.f; r[rb + 31] = 0.f;
}

// ---------------------------------------------------------------------------
// Edge aggregation in LDS, XCD-swizzled: XCD x (= blockIdx%8 round-robin) owns
// graphs [8x,8x+8) x 4 fgs -> per-XCD working set (8 graphs: r 2MB + meta 3MB)
// ~L2-sized; the 4 fg-wgs of a graph share r-lines/metadata via L2 instead of
// re-fetching from L3/HBM on 4 different XCDs. 8 lanes per edge (32B chunk),
// branchless (dropped edges: w==0 adds 0 to row 0). unroll 16 for outstanding.
// ---------------------------------------------------------------------------
__global__ __launch_bounds__(1024) void k_agg_lds(
    const int* __restrict__ src, const int* __restrict__ dst,
    const float* __restrict__ ew, const float* __restrict__ rp,
    const float* __restrict__ t, float* __restrict__ h, int n)
{
    __shared__ float acc[2048 * 8];
    int b = blockIdx.x;
    int xcd = b & 7;
    int i6 = b >> 3;                       // 0..31
    int g = xcd * 8 + (i6 & 7);
    int fg = i6 >> 3;                      // 0..3
    int f0 = fg * 8;                       // fg==3: cols 24..31 (30/31 zero pads)
    int nwr = (fg == 3) ? 6 : 8;
    int nodebase = g * n;
    for (int i = threadIdx.x; i < 2048 * 8; i += 1024) acc[i] = 0.f;
    __syncthreads();
    int gid = threadIdx.x >> 3;            // 128 groups of 8 lanes
    int lane = threadIdx.x & 7;
    int ebase = g * EPG;
#pragma unroll 16
    for (int i = 0; i < EPG / 128; ++i) {
        int e = ebase + i * 128 + gid;
        float w = ew[e];
        int s = src[e];
        int d = dst[e] - nodebase;
        d = (d < 0) ? 0 : d;               // dropped edges: dst==0, w==0 -> adds 0
        float v = rp[(size_t)s * RSTRIDE + f0 + lane] * w;
        unsafeAtomicAdd(&acc[d * 8 + lane], v);
    }
    __syncthreads();
    for (int i = threadIdx.x; i < n * 8; i += 1024) {
        int node = i >> 3, f = i & 7;
        if (f < nwr) {
            int gi = (nodebase + node) * H + f0 + f;
            h[gi] = fmaxf(acc[i] + t[gi], 0.f);
        }
    }
}

// score = tanh((h @ w) / ||w||)
__global__ __launch_bounds__(256) void k_score(
    const float* __restrict__ h, const float* __restrict__ w, float* __restrict__ score)
{
    int row = blockIdx.x * 256 + threadIdx.x;
    const float* hr = h + (size_t)row * H;
    float nw = 0.f, d = 0.f;
#pragma unroll
    for (int j = 0; j < H; ++j) {
        float wv = w[j];
        nw += wv * wv;
        d += hr[j] * wv;
    }
    score[row] = tanhf(d / sqrtf(nw));
}

// ---------------------------------------------------------------------------
// Per-graph top-k sort: bitonic sort of 2048 packed keys (desc score, asc idx)
// in LDS -- matches jax.lax.top_k tie-break. Writes sorted idx per rank only;
// the (parallel) apply/newidx kernels consume it.
// ---------------------------------------------------------------------------
__global__ __launch_bounds__(256) void k_topk_sort(
    const float* __restrict__ score, int* __restrict__ sidx, int n, int k)
{
    __shared__ unsigned long long keys[2048];
    int g = blockIdx.x;
    for (int i = threadIdx.x; i < 2048; i += 256) {
        unsigned long long key = ~0ull;
        if (i < n) {
            float s = score[g * n + i];
            if (s == 0.f) s = 0.f;                 // canonicalize -0 -> +0
            unsigned u = __float_as_uint(s);
            unsigned asc = (u & 0x80000000u) ? ~u : (u | 0x80000000u);
            unsigned desc = ~asc;                  // ascending key = descending score
            key = ((unsigned long long)desc << 32) | (unsigned)i;
        }
        keys[i] = key;
    }
    __syncthreads();
    for (int kk = 2; kk <= 2048; kk <<= 1) {
        for (int jj = kk >> 1; jj > 0; jj >>= 1) {
            for (int i = threadIdx.x; i < 2048; i += 256) {
                int ixj = i ^ jj;
                if (ixj > i) {
                    unsigned long long a = keys[i], b = keys[ixj];
                    bool up = ((i & kk) == 0);
                    if ((a > b) == up) { keys[i] = b; keys[ixj] = a; }
                }
            }
            __syncthreads();
        }
    }
    for (int j = threadIdx.x; j < k; j += 256)
        sidx[g * k + j] = (int)(keys[j] & 0xffffffffu);
}

// newidx[g*n + i] = -1 (grid.y = graph)
__global__ void k_newidx_init(int* __restrict__ newidx, int n)
{
    int i = blockIdx.x * 256 + threadIdx.x;
    if (i < n) newidx[blockIdx.y * n + i] = -1;
}

// newidx[g*n + sidx[g*k+j]] = j (grid.y = graph)
__global__ void k_newidx_set(const int* __restrict__ sidx, int* __restrict__ newidx,
                             int n, int k)
{
    int j = blockIdx.x * 256 + threadIdx.x;
    if (j < k) newidx[blockIdx.y * n + sidx[blockIdx.y * k + j]] = j;
}

// xout[g,j,f] = h[g, sidx[g,j], f] * score[g, sidx[g,j]]  (grid.y = graph)
__global__ void k_topk_apply(const int* __restrict__ sidx, const float* __restrict__ score,
                             const float* __restrict__ h, float* __restrict__ xout,
                             int n, int k)
{
    int g = blockIdx.y;
    int m = blockIdx.x * 256 + threadIdx.x;
    if (m >= k * H) return;
    int j = m / H, f = m - j * H;
    int idx = sidx[g * k + j];
    float val = score[g * n + idx];
    xout[(g * k + j) * H + f] = h[(g * n + idx) * H + f] * val;
}

// Edge remap after pooling (element-wise; safe in place).
__global__ void k_remap(const int* __restrict__ srcIn, const int* __restrict__ dstIn,
                        const float* __restrict__ ewIn, const int* __restrict__ newidx,
                        int* __restrict__ srcOut, int* __restrict__ dstOut,
                        float* __restrict__ ewOut, int nOld, int kNew)
{
    int e = blockIdx.x * 256 + threadIdx.x;
    int s = srcIn[e], d = dstIn[e];
    float w = ewIn[e];
    int g = s / nOld;
    int ns = newidx[g * nOld + (s - g * nOld)];
    int nd = newidx[g * nOld + (d % nOld)];
    bool keep = (ns >= 0) && (nd >= 0);
    srcOut[e] = keep ? g * kNew + ns : 0;
    dstOut[e] = keep ? g * kNew + nd : 0;
    ewOut[e] = keep ? w : 0.f;
}

// Per-graph readout: [max ; mean] over k rows -> out[g][0..59]
__global__ __launch_bounds__(256) void k_readout(
    const float* __restrict__ x, float* __restrict__ out, int k)
{
    __shared__ float smax[8][32], ssum[8][32];
    int g = blockIdx.x;
    int f = threadIdx.x & 31, rr = threadIdx.x >> 5;
    float mx = -INFINITY, sm = 0.f;
    if (f < H) {
        for (int row = rr; row < k; row += 8) {
            float v = x[(g * k + row) * H + f];
            mx = fmaxf(mx, v);
            sm += v;
        }
    }
    smax[rr][f] = mx; ssum[rr][f] = sm;
    __syncthreads();
    if (rr == 0 && f < H) {
        for (int q = 1; q < 8; ++q) { mx = fmaxf(mx, smax[q][f]); sm += ssum[q][f]; }
        out[g * 60 + f] = mx;
        out[g * 60 + 30 + f] = sm / (float)k;
    }
}

__global__ void k_z(const float* __restrict__ x1, const float* __restrict__ x2,
                    const float* __restrict__ x3, float* __restrict__ z)
{
    int i = blockIdx.x * 256 + threadIdx.x;
    z[i] = fmaxf(x1[i] + x2[i] + x3[i], 0.f);
}

// a1[h,b,o] = relu(sum_d z[b,d]*W1[h,d,o] + b1[h,o]),  o<240, d<60
__global__ __launch_bounds__(256) void k_mlp1(
    const float* __restrict__ z, const float* __restrict__ W,
    const float* __restrict__ bias, float* __restrict__ a)
{
    int hb = blockIdx.x, hh = hb >> 6, b = hb & 63;
    __shared__ float zr[60];
    if (threadIdx.x < 60) zr[threadIdx.x] = z[b * 60 + threadIdx.x];
    __syncthreads();
    int o = threadIdx.x;
    if (o < 240) {
        float acc = bias[hh * 240 + o];
        const float* Wp = W + hh * 60 * 240;
#pragma unroll
        for (int d = 0; d < 60; ++d) acc += zr[d] * Wp[d * 240 + o];
        a[(hh * B + b) * 240 + o] = fmaxf(acc, 0.f);
    }
}

// a2[h,b,p] = relu(sum_o a1[h,b,o]*W2[h,o,p] + b2[h,p]); blocked 8 batch rows
// per wg so each head's 0.92MB W2 streams once per 8 rows (648MB -> 10MB reqs).
__global__ __launch_bounds__(320) void k_mlp2(
    const float* __restrict__ a1, const float* __restrict__ W,
    const float* __restrict__ bias, float* __restrict__ a2)
{
    int hh = blockIdx.x >> 3;          // head (0..10)
    int bb = (blockIdx.x & 7) * 8;     // batch row block of 8
    __shared__ float ar[8][240];
    for (int i = threadIdx.x; i < 8 * 240; i += 320) {
        int rr = i / 240, o = i - rr * 240;
        ar[rr][o] = a1[(hh * B + bb + rr) * 240 + o];
    }
    __syncthreads();
    const float* Wp = W + hh * 240 * 960;
    float accv[3][8];
#pragma unroll
    for (int q = 0; q < 3; ++q)
#pragma unroll
        for (int rr = 0; rr < 8; ++rr) accv[q][rr] = 0.f;
#pragma unroll 2
    for (int o = 0; o < 240; ++o) {
        float w0 = Wp[o * 960 + threadIdx.x];
        float w1 = Wp[o * 960 + threadIdx.x + 320];
        float w2 = Wp[o * 960 + threadIdx.x + 640];
#pragma unroll
        for (int rr = 0; rr < 8; ++rr) {
            float av = ar[rr][o];
            accv[0][rr] += w0 * av;
            accv[1][rr] += w1 * av;
            accv[2][rr] += w2 * av;
        }
    }
#pragma unroll
    for (int q = 0; q < 3; ++q) {
        int p = threadIdx.x + q * 320;
        float bv = bias[hh * 960 + p];
#pragma unroll
        for (int rr = 0; rr < 8; ++rr)
            a2[(hh * B + bb + rr) * 960 + p] = fmaxf(accv[q][rr] + bv, 0.f);
    }
}

// out[h,b,q] = sum_p a2[h,b,p]*W3[h,p,q] + b3[h,q],  q<8, p<960
__global__ __launch_bounds__(64) void k_mlp3(
    const float* __restrict__ a2, const float* __restrict__ W,
    const float* __restrict__ bias, float* __restrict__ out)
{
    int hb = blockIdx.x, hh = hb >> 6, b = hb & 63;
    __shared__ float ar[960];
    __shared__ float part[64];
    for (int i = threadIdx.x; i < 960; i += 64) ar[i] = a2[(hh * B + b) * 960 + i];
    __syncthreads();
    int q = threadIdx.x & 7, c = threadIdx.x >> 3;
    const float* Wp = W + hh * 960 * 8;
    float acc = 0.f;
    for (int p = c; p < 960; p += 8) acc += ar[p] * Wp[p * 8 + q];
    part[threadIdx.x] = acc;
    __syncthreads();
    if (threadIdx.x < 8) {
        float s = bias[hh * 8 + threadIdx.x];
        for (int cc = 0; cc < 8; ++cc) s += part[cc * 8 + threadIdx.x];
        out[(hh * B + b) * 8 + threadIdx.x] = s;
    }
}

// ---------------------------------------------------------------------------
extern "C" void kernel_launch(void* const* d_in, const int* in_sizes, int n_in,
                              void* d_out, int out_size, void* d_ws, size_t ws_size,
                              hipStream_t stream)
{
    const float* x       = (const float*)d_in[0];
    const int*   eidx    = (const int*)d_in[1];
    const int*   src0    = eidx;
    const int*   dst0    = eidx + ETOT;
    const float* ew0     = (const float*)d_in[2];
    const float* ln_g    = (const float*)d_in[4];
    const float* ln_b    = (const float*)d_in[5];
    const float* W_rel1  = (const float*)d_in[6];
    const float* b_rel1  = (const float*)d_in[7];
    const float* W_root1 = (const float*)d_in[8];
    const float* W_rel2  = (const float*)d_in[9];
    const float* b_rel2  = (const float*)d_in[10];
    const float* W_root2 = (const float*)d_in[11];
    const float* W_rel3  = (const float*)d_in[12];
    const float* b_rel3  = (const float*)d_in[13];
    const float* W_root3 = (const float*)d_in[14];
    const float* pool_w1 = (const float*)d_in[15];
    const float* pool_w2 = (const float*)d_in[16];
    const float* pool_w3 = (const float*)d_in[17];
    const float* head_W1 = (const float*)d_in[18];
    const float* head_b1 = (const float*)d_in[19];
    const float* head_W2 = (const float*)d_in[20];
    const float* head_b2 = (const float*)d_in[21];
    const float* head_W3 = (const float*)d_in[22];
    const float* head_b3 = (const float*)d_in[23];

    // workspace carve (~91 MB)
    float* ws     = (float*)d_ws;
    float* rbuf   = ws;                              // NTOT*32 (padded)
    float* tbuf   = rbuf + (size_t)NTOT * RSTRIDE;   // NTOT*30
    float* abuf   = tbuf + (size_t)NTOT * H;         // NTOT*30 (h)
    float* xp     = abuf + (size_t)NTOT * H;         // NTOT*30 (pooled x)
    float* score  = xp + (size_t)NTOT * H;           // NTOT
    int*   newidx = (int*)(score + NTOT);            // NTOT
    int*   srcw   = newidx + NTOT;                   // ETOT
    int*   dstw   = srcw + ETOT;                     // ETOT
    float* eww    = (float*)(dstw + ETOT);           // ETOT
    float* x1     = eww + ETOT;                      // B*60
    float* x2     = x1 + B * 60;
    float* x3     = x2 + B * 60;
    float* zb     = x3 + B * 60;
    float* Wc1    = zb + B * 60;                     // 128*60
    float* S1     = Wc1 + IN_DIM * 60;               // 60
    float* T1     = S1 + 60;                         // 60
    float* Wc2    = T1 + 60;                         // 30*60
    float* Wc3    = Wc2 + H * 60;                    // 30*60
    int*   sidx   = (int*)(Wc3 + H * 60);            // B*2048
    float* a1     = rbuf;                            // alias: heads run after layers
    float* a2     = a1 + NH * B * 240;               // 11*64*960

    const int N2 = B * K1;   // 118016 = 461*256
    const int N3 = B * K2;   // 106240 = 415*256

    k_prep<<<1, 256, 0, stream>>>(ln_g, ln_b, W_rel1, b_rel1, W_root1,
                                  W_rel2, W_root2, W_rel3, W_root3,
                                  Wc1, S1, T1, Wc2, Wc3);

    // ---- layer 1 ----
    k_lnproj<<<NTOT / 256, 256, 0, stream>>>(x, Wc1, S1, T1, rbuf, tbuf);
    k_agg_lds<<<B * 4, 1024, 0, stream>>>(src0, dst0, ew0, rbuf, tbuf, abuf, N0);
    k_score<<<NTOT / 256, 256, 0, stream>>>(abuf, pool_w1, score);
    k_topk_sort<<<B, 256, 0, stream>>>(score, sidx, N0, K1);
    k_newidx_init<<<dim3(N0 / 256, B), 256, 0, stream>>>(newidx, N0);
    k_newidx_set<<<dim3((K1 + 255) / 256, B), 256, 0, stream>>>(sidx, newidx, N0, K1);
    k_topk_apply<<<dim3((K1 * H + 255) / 256, B), 256, 0, stream>>>(sidx, score, abuf, xp, N0, K1);
    k_remap<<<ETOT / 256, 256, 0, stream>>>(src0, dst0, ew0, newidx, srcw, dstw, eww, N0, K1);
    k_readout<<<B, 256, 0, stream>>>(xp, x1, K1);

    // ---- layer 2 ----
    k_proj30<<<N2 / 256, 256, 0, stream>>>(xp, Wc2, b_rel2, rbuf, tbuf);
    k_agg_lds<<<B * 4, 1024, 0, stream>>>(srcw, dstw, eww, rbuf, tbuf, abuf, K1);
    k_score<<<N2 / 256, 256, 0, stream>>>(abuf, pool_w2, score);
    k_topk_sort<<<B, 256, 0, stream>>>(score, sidx, K1, K2);
    k_newidx_init<<<dim3((K1 + 255) / 256, B), 256, 0, stream>>>(newidx, K1);
    k_newidx_set<<<dim3((K2 + 255) / 256, B), 256, 0, stream>>>(sidx, newidx, K1, K2);
    k_topk_apply<<<dim3((K2 * H + 255) / 256, B), 256, 0, stream>>>(sidx, score, abuf, xp, K1, K2);
    k_remap<<<ETOT / 256, 256, 0, stream>>>(srcw, dstw, eww, newidx, srcw, dstw, eww, K1, K2);
    k_readout<<<B, 256, 0, stream>>>(xp, x2, K2);

    // ---- layer 3 ----
    k_proj30<<<N3 / 256, 256, 0, stream>>>(xp, Wc3, b_rel3, rbuf, tbuf);
    k_agg_lds<<<B * 4, 1024, 0, stream>>>(srcw, dstw, eww, rbuf, tbuf, abuf, K2);
    k_score<<<N3 / 256, 256, 0, stream>>>(abuf, pool_w3, score);
    k_topk_sort<<<B, 256, 0, stream>>>(score, sidx, K2, K3);
    k_topk_apply<<<dim3((K3 * H + 255) / 256, B), 256, 0, stream>>>(sidx, score, abuf, xp, K2, K3);
    k_readout<<<B, 256, 0, stream>>>(xp, x3, K3);

    // ---- heads ----
    k_z<<<B * 60 / 256, 256, 0, stream>>>(x1, x2, x3, zb);
    k_mlp1<<<NH * B, 256, 0, stream>>>(zb, head_W1, head_b1, a1);
    k_mlp2<<<NH * 8, 320, 0, stream>>>(a1, head_W2, head_b2, a2);
    k_mlp3<<<NH * B, 64, 0, stream>>>(a2, head_W3, head_b3, (float*)d_out);
}

// Round 5
// 969.089 us; speedup vs baseline: 1.9079x; 1.7434x over previous
//
#include <hip/hip_runtime.h>
#include <hip/hip_bf16.h>

#define B 64
#define N0 2048
#define DEG 16
#define IN_DIM 128
#define H 30
#define NH 11
#define K1 1844
#define K2 1660
#define K3 1494
#define NTOT (B * N0)        /* 131072 */
#define ETOT (NTOT * DEG)    /* 2097152 */
#define EPG (ETOT / B)       /* 32768 edges per graph, contiguous */
#define RSTRIDE 32           /* padded row stride for r and h */
#define ESTRIDE1 32768       /* sorted-edge capacity per graph, layers 1&3 */
#define ESTRIDE2 27648       /* layer 2: E[live]=26567, sigma~71 -> 15-sigma margin */

// ---------------------------------------------------------------------------
// Prep: fold layernorm gamma into layer-1 weights; combine rel/root weights.
// ---------------------------------------------------------------------------
__global__ __launch_bounds__(256) void k_prep(
    const float* __restrict__ ln_g, const float* __restrict__ ln_b,
    const float* __restrict__ Wrel1, const float* __restrict__ brel1, const float* __restrict__ Wroot1,
    const float* __restrict__ Wrel2, const float* __restrict__ Wroot2,
    const float* __restrict__ Wrel3, const float* __restrict__ Wroot3,
    float* __restrict__ Wc1, float* __restrict__ S1, float* __restrict__ T1,
    float* __restrict__ Wc2, float* __restrict__ Wc3)
{
    int tid = threadIdx.x;
    for (int i = tid; i < IN_DIM * 60; i += 256) {
        int j = i / 60, c = i - j * 60;
        float w = (c < H) ? Wrel1[j * H + c] : Wroot1[j * H + (c - H)];
        Wc1[i] = w * ln_g[j];
    }
    if (tid < 60) {
        int c = tid;
        float s = 0.f, tt = 0.f;
        for (int j = 0; j < IN_DIM; ++j) {
            float w = (c < H) ? Wrel1[j * H + c] : Wroot1[j * H + (c - H)];
            s += w * ln_g[j];
            tt += w * ln_b[j];
        }
        S1[c] = s;
        T1[c] = (c < H) ? tt : tt + brel1[c - H];
    }
    for (int i = tid; i < H * 60; i += 256) {
        int j = i / 60, c = i - j * 60;
        Wc2[i] = (c < H) ? Wrel2[j * H + c] : Wroot2[j * H + (c - H)];
        Wc3[i] = (c < H) ? Wrel3[j * H + c] : Wroot3[j * H + (c - H)];
    }
}

// ---------------------------------------------------------------------------
// Layer 1: fused LayerNorm + dual projection. Thread-per-row, single pass.
// r at stride 32 (cols>=30 unused), t at stride 30.
// ---------------------------------------------------------------------------
__global__ __launch_bounds__(256) void k_lnproj(
    const float* __restrict__ x, const float* __restrict__ Wc,
    const float* __restrict__ S, const float* __restrict__ T,
    float* __restrict__ r, float* __restrict__ t)
{
    int row = blockIdx.x * 256 + threadIdx.x;
    const float* xr = x + (size_t)row * IN_DIM;
    float acc[60];
#pragma unroll
    for (int c = 0; c < 60; ++c) acc[c] = 0.f;
    float sum = 0.f, sumsq = 0.f;
    for (int jb = 0; jb < IN_DIM; jb += 8) {
        float4 a0 = *(const float4*)(xr + jb);
        float4 a1 = *(const float4*)(xr + jb + 4);
        float xs[8] = {a0.x, a0.y, a0.z, a0.w, a1.x, a1.y, a1.z, a1.w};
#pragma unroll
        for (int u = 0; u < 8; ++u) {
            float xv = xs[u];
            sum += xv;
            sumsq += xv * xv;
            const float* wrow = Wc + (jb + u) * 60;
#pragma unroll
            for (int c = 0; c < 60; ++c) acc[c] += xv * wrow[c];
        }
    }
    float mean = sum * (1.f / 128.f);
    float var = sumsq * (1.f / 128.f) - mean * mean;
    float rstd = 1.0f / sqrtf(var + 1e-5f);
    int rb = row * RSTRIDE, tb = row * H;
#pragma unroll
    for (int c = 0; c < H; ++c)
        r[rb + c] = rstd * (acc[c] - mean * S[c]) + T[c];
#pragma unroll
    for (int c = 0; c < H; ++c)
        t[tb + c] = rstd * (acc[30 + c] - mean * S[30 + c]) + T[30 + c];
}

// ---------------------------------------------------------------------------
// Pooled projection (layers 2/3): row j of pooled graph g = h[sidx]*val.
// r = (val*h)@Wrel = val*(h@Wrel); t = val*(h@Wroot) + brel. Kills topk_apply
// and the xp buffer (everything downstream is linear in the gated h).
// ---------------------------------------------------------------------------
__global__ __launch_bounds__(256) void k_proj30p(
    const float* __restrict__ hbuf, const int* __restrict__ sidx,
    const float* __restrict__ score, const float* __restrict__ Wc,
    const float* __restrict__ brel, float* __restrict__ r, float* __restrict__ t,
    int n_old, int k)
{
    int row = blockIdx.x * 256 + threadIdx.x;      // [0, B*k) exact grid
    int g = row / k, j = row - g * k;
    int idx = sidx[g * k + j];
    float val = score[g * n_old + idx];
    const float* hr = hbuf + (size_t)(g * n_old + idx) * RSTRIDE;
    float hv[32];
#pragma unroll
    for (int m = 0; m < 8; ++m) {
        float4 q = *(const float4*)(hr + m * 4);
        hv[m * 4] = q.x; hv[m * 4 + 1] = q.y; hv[m * 4 + 2] = q.z; hv[m * 4 + 3] = q.w;
    }
    float acc[60];
#pragma unroll
    for (int c = 0; c < 60; ++c) acc[c] = 0.f;
    for (int m = 0; m < H; ++m) {
        const float* wrow = Wc + m * 60;
        float xv = hv[m];
#pragma unroll
        for (int c = 0; c < 60; ++c) acc[c] += xv * wrow[c];
    }
    int rb = row * RSTRIDE, tb = row * H;
#pragma unroll
    for (int c = 0; c < H; ++c) r[rb + c] = val * acc[c];
#pragma unroll
    for (int c = 0; c < H; ++c) t[tb + c] = val * acc[30 + c] + brel[c];
}

// ---------------------------------------------------------------------------
// Counting-sort stage 1 (layer 1): per-chunk histogram of dst + per-edge rank
// (atomicAdd return). Only 1 atomic lane-op per edge (vs 30 in the old agg).
// chunk = 8192 edges; 4 chunks per graph.
// ---------------------------------------------------------------------------
__global__ __launch_bounds__(1024) void k_hist1(
    const int* __restrict__ dst, unsigned short* __restrict__ rank,
    int* __restrict__ chunkCnt)
{
    __shared__ unsigned int cnt[2048];
    int chunk = blockIdx.x, g = chunk >> 2;
    for (int i = threadIdx.x; i < 2048; i += 1024) cnt[i] = 0;
    __syncthreads();
    int e0 = chunk * 8192;
#pragma unroll
    for (int u = 0; u < 8; ++u) {
        int e = e0 + u * 1024 + threadIdx.x;
        int d = dst[e] - g * N0;
        rank[e] = (unsigned short)atomicAdd(&cnt[d], 1u);
    }
    __syncthreads();
    for (int i = threadIdx.x; i < 2048; i += 1024) chunkCnt[chunk * 2048 + i] = cnt[i];
}

// ---------------------------------------------------------------------------
// Per-graph scan: bin totals over 4 chunks -> exclusive scan (Hillis-Steele)
// -> runStart/runLen + per-chunk offsets written in-place over chunkCnt.
// ---------------------------------------------------------------------------
__global__ __launch_bounds__(1024) void k_scan(
    int* __restrict__ chunkCnt, int* __restrict__ runStart, int* __restrict__ runLen)
{
    __shared__ int bufA[2048], bufB[2048];
    int g = blockIdx.x;
    int c0[2], c1[2], c2[2], tt[2];
    for (int h2 = 0; h2 < 2; ++h2) {
        int d = threadIdx.x + h2 * 1024;
        c0[h2] = chunkCnt[(g * 4 + 0) * 2048 + d];
        c1[h2] = chunkCnt[(g * 4 + 1) * 2048 + d];
        c2[h2] = chunkCnt[(g * 4 + 2) * 2048 + d];
        int c3 = chunkCnt[(g * 4 + 3) * 2048 + d];
        tt[h2] = c0[h2] + c1[h2] + c2[h2] + c3;
        bufA[d] = tt[h2];
    }
    __syncthreads();
    int* s_ = bufA; int* d_ = bufB;
    for (int off = 1; off < 2048; off <<= 1) {
        for (int h2 = 0; h2 < 2; ++h2) {
            int d = threadIdx.x + h2 * 1024;
            int v = s_[d];
            if (d >= off) v += s_[d - off];
            d_[d] = v;
        }
        __syncthreads();
        int* tmp = s_; s_ = d_; d_ = tmp;
    }
    for (int h2 = 0; h2 < 2; ++h2) {
        int d = threadIdx.x + h2 * 1024;
        int ex = s_[d] - tt[h2];
        runStart[g * 2048 + d] = ex;
        runLen[g * 2048 + d] = tt[h2];
        chunkCnt[(g * 4 + 0) * 2048 + d] = ex;
        chunkCnt[(g * 4 + 1) * 2048 + d] = ex + c0[h2];
        chunkCnt[(g * 4 + 2) * 2048 + d] = ex + c0[h2] + c1[h2];
        chunkCnt[(g * 4 + 3) * 2048 + d] = ex + c0[h2] + c1[h2] + c2[h2];
    }
}

// Scatter (layer 1): plain writes, no atomics. Entry = (src_global_bits, w).
__global__ __launch_bounds__(1024) void k_scat1(
    const int* __restrict__ src, const int* __restrict__ dst, const float* __restrict__ ew,
    const unsigned short* __restrict__ rank, const int* __restrict__ chunkOff,
    float2* __restrict__ sOut)
{
    int chunk = blockIdx.x, g = chunk >> 2;
    int e0 = chunk * 8192;
#pragma unroll
    for (int u = 0; u < 8; ++u) {
        int e = e0 + u * 1024 + threadIdx.x;
        int d = dst[e] - g * N0;
        int pos = chunkOff[chunk * 2048 + d] + (int)rank[e];
        sOut[(size_t)g * ESTRIDE1 + pos] = make_float2(__int_as_float(src[e]), ew[e]);
    }
}

// ---------------------------------------------------------------------------
// Sort stages for layers 2/3: traverse previous layer's runs node-major with
// the newidx filter fused (kills the old k_remap). chunk = 512 old nodes,
// 2 threads per node. Bins are NEW node ids.
// ---------------------------------------------------------------------------
__global__ __launch_bounds__(1024) void k_hist2(
    const float2* __restrict__ sPrev, const int* __restrict__ runS, const int* __restrict__ runL,
    const int* __restrict__ newidx, unsigned short* __restrict__ rank,
    int* __restrict__ chunkCnt, int n_old, int estride_prev)
{
    __shared__ unsigned int cnt[2048];
    int chunk = blockIdx.x, g = chunk >> 2, q = chunk & 3;
    for (int i = threadIdx.x; i < 2048; i += 1024) cnt[i] = 0;
    __syncthreads();
    int v = q * 512 + (threadIdx.x >> 1);
    int half = threadIdx.x & 1;
    if (v < n_old) {
        int nd = newidx[g * n_old + v];
        if (nd >= 0) {
            int s0 = runS[g * 2048 + v], len = runL[g * 2048 + v];
            size_t base = (size_t)g * estride_prev + s0;
            for (int i = half; i < len; i += 2) {
                float2 m = sPrev[base + i];
                int ns = newidx[__float_as_int(m.x)];
                if (ns >= 0) rank[base + i] = (unsigned short)atomicAdd(&cnt[nd], 1u);
            }
        }
    }
    __syncthreads();
    for (int i = threadIdx.x; i < 2048; i += 1024) chunkCnt[chunk * 2048 + i] = cnt[i];
}

__global__ __launch_bounds__(1024) void k_scat2(
    const float2* __restrict__ sPrev, const int* __restrict__ runS, const int* __restrict__ runL,
    const int* __restrict__ newidx, const unsigned short* __restrict__ rank,
    const int* __restrict__ chunkOff, float2* __restrict__ sOut,
    int n_old, int estride_prev, int estride_cur, int k_new)
{
    int chunk = blockIdx.x, g = chunk >> 2, q = chunk & 3;
    int v = q * 512 + (threadIdx.x >> 1);
    int half = threadIdx.x & 1;
    if (v >= n_old) return;
    int nd = newidx[g * n_old + v];
    if (nd < 0) return;
    int s0 = runS[g * 2048 + v], len = runL[g * 2048 + v];
    size_t basep = (size_t)g * estride_prev + s0;
    int cb = chunkOff[chunk * 2048 + nd];
    size_t basec = (size_t)g * estride_cur;
    for (int i = half; i < len; i += 2) {
        float2 m = sPrev[basep + i];
        int ns = newidx[__float_as_int(m.x)];
        if (ns >= 0) {
            int pos = cb + (int)rank[basep + i];
            sOut[basec + pos] = make_float2(__int_as_float(g * k_new + ns), m.y);
        }
    }
}

// ---------------------------------------------------------------------------
// Run-major aggregation: ZERO atomics. 32 lanes per node, lane j = feature j.
// Batched-8 meta loads (broadcast) then 8 independent coalesced row gathers.
// Fused +t and relu. h at stride 32.
// ---------------------------------------------------------------------------
__global__ __launch_bounds__(256) void k_gather(
    const float2* __restrict__ sE, const int* __restrict__ runS, const int* __restrict__ runL,
    const float* __restrict__ rp, const float* __restrict__ t, float* __restrict__ h,
    int n, int estride, int nblocks)
{
    int b = blockIdx.x;
    int cpx = nblocks >> 3;                 // XCD-chunked swizzle: XCD owns contiguous graphs
    b = (b & 7) * cpx + (b >> 3);
    int slot = threadIdx.x >> 5, j = threadIdx.x & 31;
    int v = b * 8 + slot;                   // global node id (current numbering)
    int g = v / n;
    int local = v - g * n;
    int s0 = runS[g * 2048 + local], len = runL[g * 2048 + local];
    const float2* meta = sE + (size_t)g * estride + s0;
    float acc = 0.f;
    for (int c = 0; c < len; c += 8) {
        int lim = len - c; if (lim > 8) lim = 8;
        float2 m[8];
#pragma unroll
        for (int u = 0; u < 8; ++u) m[u] = meta[c + (u < lim ? u : 0)];
#pragma unroll
        for (int u = 0; u < 8; ++u) {
            int s = __float_as_int(m[u].x);
            float w = (u < lim) ? m[u].y : 0.f;
            acc += rp[(size_t)s * RSTRIDE + j] * w;
        }
    }
    if (j < H)
        h[(size_t)v * RSTRIDE + j] = fmaxf(acc + t[v * H + j], 0.f);
}

// score = tanh((h @ w) / ||w||)  (h stride 32)
__global__ __launch_bounds__(256) void k_score(
    const float* __restrict__ h, const float* __restrict__ w, float* __restrict__ score)
{
    int row = blockIdx.x * 256 + threadIdx.x;
    const float* hr = h + (size_t)row * RSTRIDE;
    float nw = 0.f, d = 0.f;
#pragma unroll
    for (int j = 0; j < H; ++j) {
        float wv = w[j];
        nw += wv * wv;
        d += hr[j] * wv;
    }
    score[row] = tanhf(d / sqrtf(nw));
}

// ---------------------------------------------------------------------------
// Per-graph top-k sort: bitonic sort of 2048 packed keys (desc score, asc idx)
// in LDS -- matches jax.lax.top_k tie-break. Writes local sorted idx per rank.
// ---------------------------------------------------------------------------
__global__ __launch_bounds__(256) void k_topk_sort(
    const float* __restrict__ score, int* __restrict__ sidx, int n, int k)
{
    __shared__ unsigned long long keys[2048];
    int g = blockIdx.x;
    for (int i = threadIdx.x; i < 2048; i += 256) {
        unsigned long long key = ~0ull;
        if (i < n) {
            float s = score[g * n + i];
            if (s == 0.f) s = 0.f;                 // canonicalize -0 -> +0
            unsigned u = __float_as_uint(s);
            unsigned asc = (u & 0x80000000u) ? ~u : (u | 0x80000000u);
            unsigned desc = ~asc;                  // ascending key = descending score
            key = ((unsigned long long)desc << 32) | (unsigned)i;
        }
        keys[i] = key;
    }
    __syncthreads();
    for (int kk = 2; kk <= 2048; kk <<= 1) {
        for (int jj = kk >> 1; jj > 0; jj >>= 1) {
            for (int i = threadIdx.x; i < 2048; i += 256) {
                int ixj = i ^ jj;
                if (ixj > i) {
                    unsigned long long a = keys[i], b = keys[ixj];
                    bool up = ((i & kk) == 0);
                    if ((a > b) == up) { keys[i] = b; keys[ixj] = a; }
                }
            }
            __syncthreads();
        }
    }
    for (int j = threadIdx.x; j < k; j += 256)
        sidx[g * k + j] = (int)(keys[j] & 0xffffffffu);
}

// newidx[g*n + i] = -1 (grid.y = graph)
__global__ void k_newidx_init(int* __restrict__ newidx, int n)
{
    int i = blockIdx.x * 256 + threadIdx.x;
    if (i < n) newidx[blockIdx.y * n + i] = -1;
}

// newidx[g*n + sidx[g*k+j]] = j (grid.y = graph)
__global__ void k_newidx_set(const int* __restrict__ sidx, int* __restrict__ newidx,
                             int n, int k)
{
    int j = blockIdx.x * 256 + threadIdx.x;
    if (j < k) newidx[blockIdx.y * n + sidx[blockIdx.y * k + j]] = j;
}

// Per-graph readout of the gated pooled rows: [max ; mean] -> out[g][0..59]
__global__ __launch_bounds__(256) void k_readoutp(
    const float* __restrict__ hbuf, const int* __restrict__ sidx,
    const float* __restrict__ score, float* __restrict__ out, int n_old, int k)
{
    __shared__ float smax[8][32], ssum[8][32];
    int g = blockIdx.x;
    int f = threadIdx.x & 31, rr = threadIdx.x >> 5;
    float mx = -INFINITY, sm = 0.f;
    if (f < H) {
        for (int jr = rr; jr < k; jr += 8) {
            int idx = sidx[g * k + jr];
            float val = score[g * n_old + idx];
            float v = hbuf[(size_t)(g * n_old + idx) * RSTRIDE + f] * val;
            mx = fmaxf(mx, v);
            sm += v;
        }
    }
    smax[rr][f] = mx; ssum[rr][f] = sm;
    __syncthreads();
    if (rr == 0 && f < H) {
        for (int q = 1; q < 8; ++q) { mx = fmaxf(mx, smax[q][f]); sm += ssum[q][f]; }
        out[g * 60 + f] = mx;
        out[g * 60 + 30 + f] = sm / (float)k;
    }
}

__global__ void k_z(const float* __restrict__ x1, const float* __restrict__ x2,
                    const float* __restrict__ x3, float* __restrict__ z)
{
    int i = blockIdx.x * 256 + threadIdx.x;
    z[i] = fmaxf(x1[i] + x2[i] + x3[i], 0.f);
}

// a1[h,b,o] = relu(sum_d z[b,d]*W1[h,d,o] + b1[h,o]),  o<240, d<60
__global__ __launch_bounds__(256) void k_mlp1(
    const float* __restrict__ z, const float* __restrict__ W,
    const float* __restrict__ bias, float* __restrict__ a)
{
    int hb = blockIdx.x, hh = hb >> 6, b = hb & 63;
    __shared__ float zr[60];
    if (threadIdx.x < 60) zr[threadIdx.x] = z[b * 60 + threadIdx.x];
    __syncthreads();
    int o = threadIdx.x;
    if (o < 240) {
        float acc = bias[hh * 240 + o];
        const float* Wp = W + hh * 60 * 240;
#pragma unroll
        for (int d = 0; d < 60; ++d) acc += zr[d] * Wp[d * 240 + o];
        a[(hh * B + b) * 240 + o] = fmaxf(acc, 0.f);
    }
}

// a2: blocked 8 batch rows per wg so each head's W2 streams once per 8 rows.
__global__ __launch_bounds__(320) void k_mlp2(
    const float* __restrict__ a1, const float* __restrict__ W,
    const float* __restrict__ bias, float* __restrict__ a2)
{
    int hh = blockIdx.x >> 3;
    int bb = (blockIdx.x & 7) * 8;
    __shared__ float ar[8][240];
    for (int i = threadIdx.x; i < 8 * 240; i += 320) {
        int rr = i / 240, o = i - rr * 240;
        ar[rr][o] = a1[(hh * B + bb + rr) * 240 + o];
    }
    __syncthreads();
    const float* Wp = W + hh * 240 * 960;
    float accv[3][8];
#pragma unroll
    for (int q = 0; q < 3; ++q)
#pragma unroll
        for (int rr = 0; rr < 8; ++rr) accv[q][rr] = 0.f;
#pragma unroll 2
    for (int o = 0; o < 240; ++o) {
        float w0 = Wp[o * 960 + threadIdx.x];
        float w1 = Wp[o * 960 + threadIdx.x + 320];
        float w2 = Wp[o * 960 + threadIdx.x + 640];
#pragma unroll
        for (int rr = 0; rr < 8; ++rr) {
            float av = ar[rr][o];
            accv[0][rr] += w0 * av;
            accv[1][rr] += w1 * av;
            accv[2][rr] += w2 * av;
        }
    }
#pragma unroll
    for (int q = 0; q < 3; ++q) {
        int p = threadIdx.x + q * 320;
        float bv = bias[hh * 960 + p];
#pragma unroll
        for (int rr = 0; rr < 8; ++rr)
            a2[(hh * B + bb + rr) * 960 + p] = fmaxf(accv[q][rr] + bv, 0.f);
    }
}

// out[h,b,q] = sum_p a2[h,b,p]*W3[h,p,q] + b3[h,q],  q<8, p<960
__global__ __launch_bounds__(64) void k_mlp3(
    const float* __restrict__ a2, const float* __restrict__ W,
    const float* __restrict__ bias, float* __restrict__ out)
{
    int hb = blockIdx.x, hh = hb >> 6, b = hb & 63;
    __shared__ float ar[960];
    __shared__ float part[64];
    for (int i = threadIdx.x; i < 960; i += 64) ar[i] = a2[(hh * B + b) * 960 + i];
    __syncthreads();
    int q = threadIdx.x & 7, c = threadIdx.x >> 3;
    const float* Wp = W + hh * 960 * 8;
    float acc = 0.f;
    for (int p = c; p < 960; p += 8) acc += ar[p] * Wp[p * 8 + q];
    part[threadIdx.x] = acc;
    __syncthreads();
    if (threadIdx.x < 8) {
        float s = bias[hh * 8 + threadIdx.x];
        for (int cc = 0; cc < 8; ++cc) s += part[cc * 8 + threadIdx.x];
        out[(hh * B + b) * 8 + threadIdx.x] = s;
    }
}

// ---------------------------------------------------------------------------
extern "C" void kernel_launch(void* const* d_in, const int* in_sizes, int n_in,
                              void* d_out, int out_size, void* d_ws, size_t ws_size,
                              hipStream_t stream)
{
    const float* x       = (const float*)d_in[0];
    const int*   eidx    = (const int*)d_in[1];
    const int*   src0    = eidx;
    const int*   dst0    = eidx + ETOT;
    const float* ew0     = (const float*)d_in[2];
    const float* ln_g    = (const float*)d_in[4];
    const float* ln_b    = (const float*)d_in[5];
    const float* W_rel1  = (const float*)d_in[6];
    const float* b_rel1  = (const float*)d_in[7];
    const float* W_root1 = (const float*)d_in[8];
    const float* W_rel2  = (const float*)d_in[9];
    const float* b_rel2  = (const float*)d_in[10];
    const float* W_root2 = (const float*)d_in[11];
    const float* W_rel3  = (const float*)d_in[12];
    const float* b_rel3  = (const float*)d_in[13];
    const float* W_root3 = (const float*)d_in[14];
    const float* pool_w1 = (const float*)d_in[15];
    const float* pool_w2 = (const float*)d_in[16];
    const float* pool_w3 = (const float*)d_in[17];
    const float* head_W1 = (const float*)d_in[18];
    const float* head_b1 = (const float*)d_in[19];
    const float* head_W2 = (const float*)d_in[20];
    const float* head_b2 = (const float*)d_in[21];
    const float* head_W3 = (const float*)d_in[22];
    const float* head_b3 = (const float*)d_in[23];

    // ---- workspace carve (~84 MB) ----
    float* ws     = (float*)d_ws;
    float* rbuf   = ws;                               // NTOT*32
    float* tbuf   = rbuf + (size_t)NTOT * RSTRIDE;    // NTOT*30
    float* abuf   = tbuf + (size_t)NTOT * H;          // NTOT*32 (h, stride 32)
    float2* sA    = (float2*)(abuf + (size_t)NTOT * RSTRIDE); // B*ESTRIDE1 entries
    float2* sB    = sA + (size_t)B * ESTRIDE1;        // B*ESTRIDE2 entries
    float* score  = (float*)(sB + (size_t)B * ESTRIDE2);      // NTOT
    int*   sidx   = (int*)(score + NTOT);             // NTOT
    int*   newidx = sidx + NTOT;                      // NTOT
    int*   runSA  = newidx + NTOT;                    // B*2048
    int*   runLA  = runSA + B * 2048;
    int*   runSB  = runLA + B * 2048;
    int*   runLB  = runSB + B * 2048;
    float* x1     = (float*)(runLB + B * 2048);       // B*60 each
    float* x2     = x1 + B * 60;
    float* x3     = x2 + B * 60;
    float* zb     = x3 + B * 60;
    float* Wc1    = zb + B * 60;                      // 128*60
    float* S1     = Wc1 + IN_DIM * 60;
    float* T1     = S1 + 60;
    float* Wc2    = T1 + 60;                          // 30*60
    float* Wc3    = Wc2 + H * 60;
    // aliases into abuf (dead h phases): chunk counters + per-edge ranks
    int* chunkBuf         = (int*)abuf;                                  // 256*2048 ints (2MB)
    unsigned short* rank  = (unsigned short*)((char*)abuf + (4u << 20)); // 2M u16 (4MB)
    // heads alias rbuf (dead after layer-3 gather)
    float* a1 = rbuf;
    float* a2 = a1 + NH * B * 240;

    k_prep<<<1, 256, 0, stream>>>(ln_g, ln_b, W_rel1, b_rel1, W_root1,
                                  W_rel2, W_root2, W_rel3, W_root3,
                                  Wc1, S1, T1, Wc2, Wc3);

    // ---- layer 1: sort + compute ----
    k_hist1<<<256, 1024, 0, stream>>>(dst0, rank, chunkBuf);
    k_scan<<<B, 1024, 0, stream>>>(chunkBuf, runSA, runLA);
    k_scat1<<<256, 1024, 0, stream>>>(src0, dst0, ew0, rank, chunkBuf, sA);
    k_lnproj<<<NTOT / 256, 256, 0, stream>>>(x, Wc1, S1, T1, rbuf, tbuf);
    k_gather<<<NTOT / 8, 256, 0, stream>>>(sA, runSA, runLA, rbuf, tbuf, abuf,
                                           N0, ESTRIDE1, NTOT / 8);
    k_score<<<NTOT / 256, 256, 0, stream>>>(abuf, pool_w1, score);
    k_topk_sort<<<B, 256, 0, stream>>>(score, sidx, N0, K1);
    k_newidx_init<<<dim3(N0 / 256, B), 256, 0, stream>>>(newidx, N0);
    k_newidx_set<<<dim3((K1 + 255) / 256, B), 256, 0, stream>>>(sidx, newidx, N0, K1);
    k_readoutp<<<B, 256, 0, stream>>>(abuf, sidx, score, x1, N0, K1);
    k_proj30p<<<B * K1 / 256, 256, 0, stream>>>(abuf, sidx, score, Wc2, b_rel2,
                                                rbuf, tbuf, N0, K1);

    // ---- layer 2: sort (reads L1 runs + newidx; rank/chunkBuf clobber dead h) ----
    k_hist2<<<256, 1024, 0, stream>>>(sA, runSA, runLA, newidx, rank, chunkBuf,
                                      N0, ESTRIDE1);
    k_scan<<<B, 1024, 0, stream>>>(chunkBuf, runSB, runLB);
    k_scat2<<<256, 1024, 0, stream>>>(sA, runSA, runLA, newidx, rank, chunkBuf, sB,
                                      N0, ESTRIDE1, ESTRIDE2, K1);
    k_gather<<<B * K1 / 8, 256, 0, stream>>>(sB, runSB, runLB, rbuf, tbuf, abuf,
                                             K1, ESTRIDE2, B * K1 / 8);
    k_score<<<B * K1 / 256, 256, 0, stream>>>(abuf, pool_w2, score);
    k_topk_sort<<<B, 256, 0, stream>>>(score, sidx, K1, K2);
    k_newidx_init<<<dim3((K1 + 255) / 256, B), 256, 0, stream>>>(newidx, K1);
    k_newidx_set<<<dim3((K2 + 255) / 256, B), 256, 0, stream>>>(sidx, newidx, K1, K2);
    k_readoutp<<<B, 256, 0, stream>>>(abuf, sidx, score, x2, K1, K2);
    k_proj30p<<<B * K2 / 256, 256, 0, stream>>>(abuf, sidx, score, Wc3, b_rel3,
                                                rbuf, tbuf, K1, K2);

    // ---- layer 3: sort (reads L2 runs; output into sA, L1 sorted is dead) ----
    k_hist2<<<256, 1024, 0, stream>>>(sB, runSB, runLB, newidx, rank, chunkBuf,
                                      K1, ESTRIDE2);
    k_scan<<<B, 1024, 0, stream>>>(chunkBuf, runSA, runLA);
    k_scat2<<<256, 1024, 0, stream>>>(sB, runSB, runLB, newidx, rank, chunkBuf, sA,
                                      K1, ESTRIDE2, ESTRIDE1, K2);
    k_gather<<<B * K2 / 8, 256, 0, stream>>>(sA, runSA, runLA, rbuf, tbuf, abuf,
                                             K2, ESTRIDE1, B * K2 / 8);
    k_score<<<B * K2 / 256, 256, 0, stream>>>(abuf, pool_w3, score);
    k_topk_sort<<<B, 256, 0, stream>>>(score, sidx, K2, K3);
    k_readoutp<<<B, 256, 0, stream>>>(abuf, sidx, score, x3, K2, K3);

    // ---- heads ----
    k_z<<<B * 60 / 256, 256, 0, stream>>>(x1, x2, x3, zb);
    k_mlp1<<<NH * B, 256, 0, stream>>>(zb, head_W1, head_b1, a1);
    k_mlp2<<<NH * 8, 320, 0, stream>>>(a1, head_W2, head_b2, a2);
    k_mlp3<<<NH * B, 64, 0, stream>>>(a2, head_W3, head_b3, (float*)d_out);
}

// Round 6
// 577.209 us; speedup vs baseline: 3.2032x; 1.6789x over previous
//
#include <hip/hip_runtime.h>
#include <hip/hip_bf16.h>

#define B 64
#define N0 2048
#define DEG 16
#define IN_DIM 128
#define H 30
#define NH 11
#define K1 1844
#define K2 1660
#define K3 1494
#define NTOT (B * N0)        /* 131072 */
#define ETOT (NTOT * DEG)    /* 2097152 */
#define EPG (ETOT / B)       /* 32768 edges per graph, contiguous */
#define RSTRIDE 32           /* padded row stride for r and h */
#define ESTRIDE1 32768       /* sorted-edge capacity per graph, layers 1&3 */
#define ESTRIDE2 27648       /* layer 2: E[live]=26567, sigma~71 -> 15-sigma margin */
#define RSEG 16              /* readout segments per graph */

// ---------------------------------------------------------------------------
// Prep: fold layernorm gamma into layer-1 weights; combine rel/root weights.
// ---------------------------------------------------------------------------
__global__ __launch_bounds__(256) void k_prep(
    const float* __restrict__ ln_g, const float* __restrict__ ln_b,
    const float* __restrict__ Wrel1, const float* __restrict__ brel1, const float* __restrict__ Wroot1,
    const float* __restrict__ Wrel2, const float* __restrict__ Wroot2,
    const float* __restrict__ Wrel3, const float* __restrict__ Wroot3,
    float* __restrict__ Wc1, float* __restrict__ S1, float* __restrict__ T1,
    float* __restrict__ Wc2, float* __restrict__ Wc3)
{
    int tid = threadIdx.x;
    for (int i = tid; i < IN_DIM * 60; i += 256) {
        int j = i / 60, c = i - j * 60;
        float w = (c < H) ? Wrel1[j * H + c] : Wroot1[j * H + (c - H)];
        Wc1[i] = w * ln_g[j];
    }
    if (tid < 60) {
        int c = tid;
        float s = 0.f, tt = 0.f;
        for (int j = 0; j < IN_DIM; ++j) {
            float w = (c < H) ? Wrel1[j * H + c] : Wroot1[j * H + (c - H)];
            s += w * ln_g[j];
            tt += w * ln_b[j];
        }
        S1[c] = s;
        T1[c] = (c < H) ? tt : tt + brel1[c - H];
    }
    for (int i = tid; i < H * 60; i += 256) {
        int j = i / 60, c = i - j * 60;
        Wc2[i] = (c < H) ? Wrel2[j * H + c] : Wroot2[j * H + (c - H)];
        Wc3[i] = (c < H) ? Wrel3[j * H + c] : Wroot3[j * H + (c - H)];
    }
}

// ---------------------------------------------------------------------------
// Layer 1: fused LayerNorm + dual projection. Thread-per-row, single pass.
// ---------------------------------------------------------------------------
__global__ __launch_bounds__(256) void k_lnproj(
    const float* __restrict__ x, const float* __restrict__ Wc,
    const float* __restrict__ S, const float* __restrict__ T,
    float* __restrict__ r, float* __restrict__ t)
{
    int row = blockIdx.x * 256 + threadIdx.x;
    const float* xr = x + (size_t)row * IN_DIM;
    float acc[60];
#pragma unroll
    for (int c = 0; c < 60; ++c) acc[c] = 0.f;
    float sum = 0.f, sumsq = 0.f;
    for (int jb = 0; jb < IN_DIM; jb += 8) {
        float4 a0 = *(const float4*)(xr + jb);
        float4 a1 = *(const float4*)(xr + jb + 4);
        float xs[8] = {a0.x, a0.y, a0.z, a0.w, a1.x, a1.y, a1.z, a1.w};
#pragma unroll
        for (int u = 0; u < 8; ++u) {
            float xv = xs[u];
            sum += xv;
            sumsq += xv * xv;
            const float* wrow = Wc + (jb + u) * 60;
#pragma unroll
            for (int c = 0; c < 60; ++c) acc[c] += xv * wrow[c];
        }
    }
    float mean = sum * (1.f / 128.f);
    float var = sumsq * (1.f / 128.f) - mean * mean;
    float rstd = 1.0f / sqrtf(var + 1e-5f);
    int rb = row * RSTRIDE, tb = row * H;
#pragma unroll
    for (int c = 0; c < H; ++c)
        r[rb + c] = rstd * (acc[c] - mean * S[c]) + T[c];
#pragma unroll
    for (int c = 0; c < H; ++c)
        t[tb + c] = rstd * (acc[30 + c] - mean * S[30 + c]) + T[30 + c];
}

// ---------------------------------------------------------------------------
// Pooled projection (layers 2/3): r = val*(h@Wrel); t = val*(h@Wroot) + brel.
// ---------------------------------------------------------------------------
__global__ __launch_bounds__(256) void k_proj30p(
    const float* __restrict__ hbuf, const int* __restrict__ sidx,
    const float* __restrict__ score, const float* __restrict__ Wc,
    const float* __restrict__ brel, float* __restrict__ r, float* __restrict__ t,
    int n_old, int k)
{
    int row = blockIdx.x * 256 + threadIdx.x;      // [0, B*k) exact grid
    int g = row / k, j = row - g * k;
    int idx = sidx[g * k + j];
    float val = score[g * n_old + idx];
    const float* hr = hbuf + (size_t)(g * n_old + idx) * RSTRIDE;
    float hv[32];
#pragma unroll
    for (int m = 0; m < 8; ++m) {
        float4 q = *(const float4*)(hr + m * 4);
        hv[m * 4] = q.x; hv[m * 4 + 1] = q.y; hv[m * 4 + 2] = q.z; hv[m * 4 + 3] = q.w;
    }
    float acc[60];
#pragma unroll
    for (int c = 0; c < 60; ++c) acc[c] = 0.f;
    for (int m = 0; m < H; ++m) {
        const float* wrow = Wc + m * 60;
        float xv = hv[m];
#pragma unroll
        for (int c = 0; c < 60; ++c) acc[c] += xv * wrow[c];
    }
    int rb = row * RSTRIDE, tb = row * H;
#pragma unroll
    for (int c = 0; c < H; ++c) r[rb + c] = val * acc[c];
#pragma unroll
    for (int c = 0; c < H; ++c) t[tb + c] = val * acc[30 + c] + brel[c];
}

// ---------------------------------------------------------------------------
// Counting-sort stage 1 (layer 1): per-chunk histogram of dst + per-edge rank.
// chunk = 8192 edges; 4 chunks per graph.
// ---------------------------------------------------------------------------
__global__ __launch_bounds__(1024) void k_hist1(
    const int* __restrict__ dst, unsigned short* __restrict__ rank,
    int* __restrict__ chunkCnt)
{
    __shared__ unsigned int cnt[2048];
    int chunk = blockIdx.x, g = chunk >> 2;
    for (int i = threadIdx.x; i < 2048; i += 1024) cnt[i] = 0;
    __syncthreads();
    int e0 = chunk * 8192;
#pragma unroll
    for (int u = 0; u < 8; ++u) {
        int e = e0 + u * 1024 + threadIdx.x;
        int d = dst[e] - g * N0;
        rank[e] = (unsigned short)atomicAdd(&cnt[d], 1u);
    }
    __syncthreads();
    for (int i = threadIdx.x; i < 2048; i += 1024) chunkCnt[chunk * 2048 + i] = cnt[i];
}

// Scatter (layer 1): plain writes, no atomics. Entry = (src_global_bits, w).
__global__ __launch_bounds__(1024) void k_scat1(
    const int* __restrict__ src, const int* __restrict__ dst, const float* __restrict__ ew,
    const unsigned short* __restrict__ rank, const int* __restrict__ chunkOff,
    float2* __restrict__ sOut)
{
    int chunk = blockIdx.x, g = chunk >> 2;
    int e0 = chunk * 8192;
#pragma unroll
    for (int u = 0; u < 8; ++u) {
        int e = e0 + u * 1024 + threadIdx.x;
        int d = dst[e] - g * N0;
        int pos = chunkOff[chunk * 2048 + d] + (int)rank[e];
        sOut[(size_t)g * ESTRIDE1 + pos] = make_float2(__int_as_float(src[e]), ew[e]);
    }
}

// ---------------------------------------------------------------------------
// Layers 2/3 sort from the ORIGINAL edge list + cumulative map (v0 -> current
// id or -1). Fully parallel & coalesced; bin = map[dst0]. 1 atomic/live edge.
// ---------------------------------------------------------------------------
__global__ __launch_bounds__(1024) void k_histE(
    const int* __restrict__ src0, const int* __restrict__ dst0,
    const int* __restrict__ mapc, unsigned short* __restrict__ rank,
    int* __restrict__ chunkCnt)
{
    __shared__ unsigned int cnt[2048];
    int chunk = blockIdx.x;
    for (int i = threadIdx.x; i < 2048; i += 1024) cnt[i] = 0;
    __syncthreads();
    int e0 = chunk * 8192;
#pragma unroll
    for (int u = 0; u < 8; ++u) {
        int e = e0 + u * 1024 + threadIdx.x;
        int dd = mapc[dst0[e]];
        int ss = mapc[src0[e]];
        if (dd >= 0 && ss >= 0)
            rank[e] = (unsigned short)atomicAdd(&cnt[dd], 1u);
    }
    __syncthreads();
    for (int i = threadIdx.x; i < 2048; i += 1024) chunkCnt[chunk * 2048 + i] = cnt[i];
}

__global__ __launch_bounds__(1024) void k_scatE(
    const int* __restrict__ src0, const int* __restrict__ dst0,
    const float* __restrict__ ew, const int* __restrict__ mapc,
    const unsigned short* __restrict__ rank, const int* __restrict__ chunkOff,
    float2* __restrict__ sOut, int k_new, int estride)
{
    int chunk = blockIdx.x, g = chunk >> 2;
    int e0 = chunk * 8192;
#pragma unroll
    for (int u = 0; u < 8; ++u) {
        int e = e0 + u * 1024 + threadIdx.x;
        int dd = mapc[dst0[e]];
        int ss = mapc[src0[e]];
        if (dd >= 0 && ss >= 0) {
            int pos = chunkOff[chunk * 2048 + dd] + (int)rank[e];
            sOut[(size_t)g * estride + pos] =
                make_float2(__int_as_float(g * k_new + ss), ew[e]);
        }
    }
}

// ---------------------------------------------------------------------------
// Per-graph scan: bin totals over 4 chunks -> exclusive scan -> runStart/Len
// + per-chunk offsets written in-place over chunkCnt.
// ---------------------------------------------------------------------------
__global__ __launch_bounds__(1024) void k_scan(
    int* __restrict__ chunkCnt, int* __restrict__ runStart, int* __restrict__ runLen)
{
    __shared__ int bufA[2048], bufB[2048];
    int g = blockIdx.x;
    int c0[2], c1[2], c2[2], tt[2];
    for (int h2 = 0; h2 < 2; ++h2) {
        int d = threadIdx.x + h2 * 1024;
        c0[h2] = chunkCnt[(g * 4 + 0) * 2048 + d];
        c1[h2] = chunkCnt[(g * 4 + 1) * 2048 + d];
        c2[h2] = chunkCnt[(g * 4 + 2) * 2048 + d];
        int c3 = chunkCnt[(g * 4 + 3) * 2048 + d];
        tt[h2] = c0[h2] + c1[h2] + c2[h2] + c3;
        bufA[d] = tt[h2];
    }
    __syncthreads();
    int* s_ = bufA; int* d_ = bufB;
    for (int off = 1; off < 2048; off <<= 1) {
        for (int h2 = 0; h2 < 2; ++h2) {
            int d = threadIdx.x + h2 * 1024;
            int v = s_[d];
            if (d >= off) v += s_[d - off];
            d_[d] = v;
        }
        __syncthreads();
        int* tmp = s_; s_ = d_; d_ = tmp;
    }
    for (int h2 = 0; h2 < 2; ++h2) {
        int d = threadIdx.x + h2 * 1024;
        int ex = s_[d] - tt[h2];
        runStart[g * 2048 + d] = ex;
        runLen[g * 2048 + d] = tt[h2];
        chunkCnt[(g * 4 + 0) * 2048 + d] = ex;
        chunkCnt[(g * 4 + 1) * 2048 + d] = ex + c0[h2];
        chunkCnt[(g * 4 + 2) * 2048 + d] = ex + c0[h2] + c1[h2];
        chunkCnt[(g * 4 + 3) * 2048 + d] = ex + c0[h2] + c1[h2] + c2[h2];
    }
}

// ---------------------------------------------------------------------------
// Run-major aggregation, ZERO atomics, fused +t/relu AND fused score:
// 32 lanes per node (lane j = feature j); after h is computed, a 32-lane
// shfl_xor reduce computes tanh(h.w/||w||) and lane 0 writes score.
// ---------------------------------------------------------------------------
__global__ __launch_bounds__(256) void k_gather(
    const float2* __restrict__ sE, const int* __restrict__ runS, const int* __restrict__ runL,
    const float* __restrict__ rp, const float* __restrict__ t, float* __restrict__ h,
    const float* __restrict__ poolw, float* __restrict__ score,
    int n, int estride, int nblocks)
{
    int b = blockIdx.x;
    int cpx = nblocks >> 3;                 // XCD-chunked swizzle
    b = (b & 7) * cpx + (b >> 3);
    int slot = threadIdx.x >> 5, j = threadIdx.x & 31;
    int v = b * 8 + slot;
    int g = v / n;
    int local = v - g * n;
    int s0 = runS[g * 2048 + local], len = runL[g * 2048 + local];
    const float2* meta = sE + (size_t)g * estride + s0;
    float acc = 0.f;
    for (int c = 0; c < len; c += 8) {
        int lim = len - c; if (lim > 8) lim = 8;
        float2 m[8];
#pragma unroll
        for (int u = 0; u < 8; ++u) m[u] = meta[c + (u < lim ? u : 0)];
#pragma unroll
        for (int u = 0; u < 8; ++u) {
            int s = __float_as_int(m[u].x);
            float w = (u < lim) ? m[u].y : 0.f;
            acc += rp[(size_t)s * RSTRIDE + j] * w;
        }
    }
    float wj = (j < H) ? poolw[j] : 0.f;
    float hval = 0.f;
    if (j < H) {
        hval = fmaxf(acc + t[v * H + j], 0.f);
        h[(size_t)v * RSTRIDE + j] = hval;
    }
    float p = hval * wj, q = wj * wj;
#pragma unroll
    for (int off = 16; off > 0; off >>= 1) {
        p += __shfl_xor(p, off, 32);
        q += __shfl_xor(q, off, 32);
    }
    if (j == 0) score[v] = tanhf(p / sqrtf(q));
}

// ---------------------------------------------------------------------------
// Top-k (desc score, asc idx; matches jax.lax.top_k tie-break) + fused
// newidx/map update: builds inv[] in LDS, writes sidx, and updates the
// cumulative map v0 -> current id in place.
// ---------------------------------------------------------------------------
__global__ __launch_bounds__(1024) void k_topk_map(
    const float* __restrict__ score, int* __restrict__ sidx, int* __restrict__ mapc,
    int n, int k, int first)
{
    __shared__ unsigned long long keys[2048];
    __shared__ int inv[2048];
    int g = blockIdx.x;
    for (int i = threadIdx.x; i < 2048; i += 1024) {
        unsigned long long key = ~0ull;
        if (i < n) {
            float s = score[g * n + i];
            if (s == 0.f) s = 0.f;                 // canonicalize -0 -> +0
            unsigned u = __float_as_uint(s);
            unsigned asc = (u & 0x80000000u) ? ~u : (u | 0x80000000u);
            unsigned desc = ~asc;
            key = ((unsigned long long)desc << 32) | (unsigned)i;
        }
        keys[i] = key;
        inv[i] = -1;
    }
    __syncthreads();
    for (int kk = 2; kk <= 2048; kk <<= 1) {
        for (int jj = kk >> 1; jj > 0; jj >>= 1) {
            for (int i = threadIdx.x; i < 2048; i += 1024) {
                int ixj = i ^ jj;
                if (ixj > i) {
                    unsigned long long a = keys[i], bb = keys[ixj];
                    bool up = ((i & kk) == 0);
                    if ((a > bb) == up) { keys[i] = bb; keys[ixj] = a; }
                }
            }
            __syncthreads();
        }
    }
    for (int j = threadIdx.x; j < k; j += 1024) {
        int idx = (int)(keys[j] & 0xffffffffu);
        sidx[g * k + j] = idx;
        inv[idx] = j;
    }
    __syncthreads();
    if (first) {
        for (int v = threadIdx.x; v < N0; v += 1024)
            mapc[g * N0 + v] = inv[v];
    } else {
        for (int v = threadIdx.x; v < N0; v += 1024) {
            int m = mapc[g * N0 + v];
            mapc[g * N0 + v] = (m >= 0) ? inv[m] : -1;
        }
    }
}

// ---------------------------------------------------------------------------
// Segmented readout: grid (RSEG, B). Partial [max;sum] over a row slice.
// ---------------------------------------------------------------------------
__global__ __launch_bounds__(256) void k_rpart(
    const float* __restrict__ hbuf, const int* __restrict__ sidx,
    const float* __restrict__ score, float* __restrict__ pmax, float* __restrict__ psum,
    int n_old, int k)
{
    __shared__ float smax[8][32], ssum[8][32];
    int g = blockIdx.y, seg = blockIdx.x;
    int clen = (k + RSEG - 1) / RSEG;
    int start = seg * clen;
    int end = start + clen; if (end > k) end = k;
    int f = threadIdx.x & 31, rr = threadIdx.x >> 5;
    float mx = -INFINITY, sm = 0.f;
    if (f < H) {
        for (int j = start + rr; j < end; j += 8) {
            int idx = sidx[g * k + j];
            float val = score[g * n_old + idx];
            float v = hbuf[(size_t)(g * n_old + idx) * RSTRIDE + f] * val;
            mx = fmaxf(mx, v);
            sm += v;
        }
    }
    smax[rr][f] = mx; ssum[rr][f] = sm;
    __syncthreads();
    if (rr == 0) {
        for (int q = 1; q < 8; ++q) { mx = fmaxf(mx, smax[q][f]); sm += ssum[q][f]; }
        pmax[(g * RSEG + seg) * 32 + f] = mx;
        psum[(g * RSEG + seg) * 32 + f] = sm;
    }
}

// Finalize all 3 readouts + z = relu(x1+x2+x3). grid B, block 64.
__global__ __launch_bounds__(64) void k_zfin(
    const float* __restrict__ pm1, const float* __restrict__ ps1,
    const float* __restrict__ pm2, const float* __restrict__ ps2,
    const float* __restrict__ pm3, const float* __restrict__ ps3,
    float* __restrict__ z)
{
    int g = blockIdx.x, c = threadIdx.x;
    if (c >= 60) return;
    float v1, v2, v3;
    if (c < H) {
        float m1 = -INFINITY, m2 = -INFINITY, m3 = -INFINITY;
        for (int s = 0; s < RSEG; ++s) {
            m1 = fmaxf(m1, pm1[(g * RSEG + s) * 32 + c]);
            m2 = fmaxf(m2, pm2[(g * RSEG + s) * 32 + c]);
            m3 = fmaxf(m3, pm3[(g * RSEG + s) * 32 + c]);
        }
        v1 = m1; v2 = m2; v3 = m3;
    } else {
        int f = c - H;
        float s1 = 0.f, s2 = 0.f, s3 = 0.f;
        for (int s = 0; s < RSEG; ++s) {
            s1 += ps1[(g * RSEG + s) * 32 + f];
            s2 += ps2[(g * RSEG + s) * 32 + f];
            s3 += ps3[(g * RSEG + s) * 32 + f];
        }
        v1 = s1 / (float)K1; v2 = s2 / (float)K2; v3 = s3 / (float)K3;
    }
    z[g * 60 + c] = fmaxf(v1 + v2 + v3, 0.f);
}

// a1[h,b,o] = relu(sum_d z[b,d]*W1[h,d,o] + b1[h,o]),  o<240, d<60
__global__ __launch_bounds__(256) void k_mlp1(
    const float* __restrict__ z, const float* __restrict__ W,
    const float* __restrict__ bias, float* __restrict__ a)
{
    int hb = blockIdx.x, hh = hb >> 6, b = hb & 63;
    __shared__ float zr[60];
    if (threadIdx.x < 60) zr[threadIdx.x] = z[b * 60 + threadIdx.x];
    __syncthreads();
    int o = threadIdx.x;
    if (o < 240) {
        float acc = bias[hh * 240 + o];
        const float* Wp = W + hh * 60 * 240;
#pragma unroll
        for (int d = 0; d < 60; ++d) acc += zr[d] * Wp[d * 240 + o];
        a[(hh * B + b) * 240 + o] = fmaxf(acc, 0.f);
    }
}

// a2: blocked 8 batch rows per wg so each head's W2 streams once per 8 rows.
__global__ __launch_bounds__(320) void k_mlp2(
    const float* __restrict__ a1, const float* __restrict__ W,
    const float* __restrict__ bias, float* __restrict__ a2)
{
    int hh = blockIdx.x >> 3;
    int bb = (blockIdx.x & 7) * 8;
    __shared__ float ar[8][240];
    for (int i = threadIdx.x; i < 8 * 240; i += 320) {
        int rr = i / 240, o = i - rr * 240;
        ar[rr][o] = a1[(hh * B + bb + rr) * 240 + o];
    }
    __syncthreads();
    const float* Wp = W + hh * 240 * 960;
    float accv[3][8];
#pragma unroll
    for (int q = 0; q < 3; ++q)
#pragma unroll
        for (int rr = 0; rr < 8; ++rr) accv[q][rr] = 0.f;
#pragma unroll 2
    for (int o = 0; o < 240; ++o) {
        float w0 = Wp[o * 960 + threadIdx.x];
        float w1 = Wp[o * 960 + threadIdx.x + 320];
        float w2 = Wp[o * 960 + threadIdx.x + 640];
#pragma unroll
        for (int rr = 0; rr < 8; ++rr) {
            float av = ar[rr][o];
            accv[0][rr] += w0 * av;
            accv[1][rr] += w1 * av;
            accv[2][rr] += w2 * av;
        }
    }
#pragma unroll
    for (int q = 0; q < 3; ++q) {
        int p = threadIdx.x + q * 320;
        float bv = bias[hh * 960 + p];
#pragma unroll
        for (int rr = 0; rr < 8; ++rr)
            a2[(hh * B + bb + rr) * 960 + p] = fmaxf(accv[q][rr] + bv, 0.f);
    }
}

// out[h,b,q] = sum_p a2[h,b,p]*W3[h,p,q] + b3[h,q],  q<8, p<960
__global__ __launch_bounds__(64) void k_mlp3(
    const float* __restrict__ a2, const float* __restrict__ W,
    const float* __restrict__ bias, float* __restrict__ out)
{
    int hb = blockIdx.x, hh = hb >> 6, b = hb & 63;
    __shared__ float ar[960];
    __shared__ float part[64];
    for (int i = threadIdx.x; i < 960; i += 64) ar[i] = a2[(hh * B + b) * 960 + i];
    __syncthreads();
    int q = threadIdx.x & 7, c = threadIdx.x >> 3;
    const float* Wp = W + hh * 960 * 8;
    float acc = 0.f;
    for (int p = c; p < 960; p += 8) acc += ar[p] * Wp[p * 8 + q];
    part[threadIdx.x] = acc;
    __syncthreads();
    if (threadIdx.x < 8) {
        float s = bias[hh * 8 + threadIdx.x];
        for (int cc = 0; cc < 8; ++cc) s += part[cc * 8 + threadIdx.x];
        out[(hh * B + b) * 8 + threadIdx.x] = s;
    }
}

// ---------------------------------------------------------------------------
extern "C" void kernel_launch(void* const* d_in, const int* in_sizes, int n_in,
                              void* d_out, int out_size, void* d_ws, size_t ws_size,
                              hipStream_t stream)
{
    const float* x       = (const float*)d_in[0];
    const int*   eidx    = (const int*)d_in[1];
    const int*   src0    = eidx;
    const int*   dst0    = eidx + ETOT;
    const float* ew0     = (const float*)d_in[2];
    const float* ln_g    = (const float*)d_in[4];
    const float* ln_b    = (const float*)d_in[5];
    const float* W_rel1  = (const float*)d_in[6];
    const float* b_rel1  = (const float*)d_in[7];
    const float* W_root1 = (const float*)d_in[8];
    const float* W_rel2  = (const float*)d_in[9];
    const float* b_rel2  = (const float*)d_in[10];
    const float* W_root2 = (const float*)d_in[11];
    const float* W_rel3  = (const float*)d_in[12];
    const float* b_rel3  = (const float*)d_in[13];
    const float* W_root3 = (const float*)d_in[14];
    const float* pool_w1 = (const float*)d_in[15];
    const float* pool_w2 = (const float*)d_in[16];
    const float* pool_w3 = (const float*)d_in[17];
    const float* head_W1 = (const float*)d_in[18];
    const float* head_b1 = (const float*)d_in[19];
    const float* head_W2 = (const float*)d_in[20];
    const float* head_b2 = (const float*)d_in[21];
    const float* head_W3 = (const float*)d_in[22];
    const float* head_b3 = (const float*)d_in[23];

    // ---- workspace carve (~82 MB) ----
    float* ws     = (float*)d_ws;
    float* rbuf   = ws;                               // NTOT*32
    float* tbuf   = rbuf + (size_t)NTOT * RSTRIDE;    // NTOT*30
    float* abuf   = tbuf + (size_t)NTOT * H;          // NTOT*32 (h, stride 32)
    float2* sA    = (float2*)(abuf + (size_t)NTOT * RSTRIDE); // B*ESTRIDE1
    float2* sB    = sA + (size_t)B * ESTRIDE1;        // B*ESTRIDE2
    float* score  = (float*)(sB + (size_t)B * ESTRIDE2);      // NTOT
    int*   sidx   = (int*)(score + NTOT);             // NTOT
    int*   mapc   = sidx + NTOT;                      // NTOT (v0 -> current id)
    int*   runSA  = mapc + NTOT;                      // B*2048 each
    int*   runLA  = runSA + B * 2048;
    int*   runSB  = runLA + B * 2048;
    int*   runLB  = runSB + B * 2048;
    float* pm1    = (float*)(runLB + B * 2048);       // B*RSEG*32 each
    float* ps1    = pm1 + B * RSEG * 32;
    float* pm2    = ps1 + B * RSEG * 32;
    float* ps2    = pm2 + B * RSEG * 32;
    float* pm3    = ps2 + B * RSEG * 32;
    float* ps3    = pm3 + B * RSEG * 32;
    float* zb     = ps3 + B * RSEG * 32;              // B*60
    float* Wc1    = zb + B * 60;                      // 128*60
    float* S1     = Wc1 + IN_DIM * 60;
    float* T1     = S1 + 60;
    float* Wc2    = T1 + 60;                          // 30*60
    float* Wc3    = Wc2 + H * 60;
    // aliases into abuf (dead h phases): chunk counters + per-edge ranks
    int* chunkBuf         = (int*)abuf;                                  // 256*2048 ints
    unsigned short* rank  = (unsigned short*)((char*)abuf + (4u << 20)); // ETOT u16
    // heads alias rbuf (dead after layer-3 gather)
    float* a1 = rbuf;
    float* a2 = a1 + NH * B * 240;

    k_prep<<<1, 256, 0, stream>>>(ln_g, ln_b, W_rel1, b_rel1, W_root1,
                                  W_rel2, W_root2, W_rel3, W_root3,
                                  Wc1, S1, T1, Wc2, Wc3);

    // ---- layer 1 ----
    k_hist1<<<256, 1024, 0, stream>>>(dst0, rank, chunkBuf);
    k_scan<<<B, 1024, 0, stream>>>(chunkBuf, runSA, runLA);
    k_scat1<<<256, 1024, 0, stream>>>(src0, dst0, ew0, rank, chunkBuf, sA);
    k_lnproj<<<NTOT / 256, 256, 0, stream>>>(x, Wc1, S1, T1, rbuf, tbuf);
    k_gather<<<NTOT / 8, 256, 0, stream>>>(sA, runSA, runLA, rbuf, tbuf, abuf,
                                           pool_w1, score, N0, ESTRIDE1, NTOT / 8);
    k_topk_map<<<B, 1024, 0, stream>>>(score, sidx, mapc, N0, K1, 1);
    k_rpart<<<dim3(RSEG, B), 256, 0, stream>>>(abuf, sidx, score, pm1, ps1, N0, K1);
    k_proj30p<<<B * K1 / 256, 256, 0, stream>>>(abuf, sidx, score, Wc2, b_rel2,
                                                rbuf, tbuf, N0, K1);

    // ---- layer 2 ----
    k_histE<<<256, 1024, 0, stream>>>(src0, dst0, mapc, rank, chunkBuf);
    k_scan<<<B, 1024, 0, stream>>>(chunkBuf, runSB, runLB);
    k_scatE<<<256, 1024, 0, stream>>>(src0, dst0, ew0, mapc, rank, chunkBuf, sB,
                                      K1, ESTRIDE2);
    k_gather<<<B * K1 / 8, 256, 0, stream>>>(sB, runSB, runLB, rbuf, tbuf, abuf,
                                             pool_w2, score, K1, ESTRIDE2, B * K1 / 8);
    k_topk_map<<<B, 1024, 0, stream>>>(score, sidx, mapc, K1, K2, 0);
    k_rpart<<<dim3(RSEG, B), 256, 0, stream>>>(abuf, sidx, score, pm2, ps2, K1, K2);
    k_proj30p<<<B * K2 / 256, 256, 0, stream>>>(abuf, sidx, score, Wc3, b_rel3,
                                                rbuf, tbuf, K1, K2);

    // ---- layer 3 ----
    k_histE<<<256, 1024, 0, stream>>>(src0, dst0, mapc, rank, chunkBuf);
    k_scan<<<B, 1024, 0, stream>>>(chunkBuf, runSA, runLA);
    k_scatE<<<256, 1024, 0, stream>>>(src0, dst0, ew0, mapc, rank, chunkBuf, sA,
                                      K2, ESTRIDE1);
    k_gather<<<B * K2 / 8, 256, 0, stream>>>(sA, runSA, runLA, rbuf, tbuf, abuf,
                                             pool_w3, score, K2, ESTRIDE1, B * K2 / 8);
    k_topk_map<<<B, 1024, 0, stream>>>(score, sidx, mapc, K2, K3, 0);
    k_rpart<<<dim3(RSEG, B), 256, 0, stream>>>(abuf, sidx, score, pm3, ps3, K2, K3);

    // ---- heads ----
    k_zfin<<<B, 64, 0, stream>>>(pm1, ps1, pm2, ps2, pm3, ps3, zb);
    k_mlp1<<<NH * B, 256, 0, stream>>>(zb, head_W1, head_b1, a1);
    k_mlp2<<<NH * 8, 320, 0, stream>>>(a1, head_W2, head_b2, a2);
    k_mlp3<<<NH * B, 64, 0, stream>>>(a2, head_W3, head_b3, (float*)d_out);
}

// Round 7
// 557.184 us; speedup vs baseline: 3.3183x; 1.0359x over previous
//
#include <hip/hip_runtime.h>
#include <hip/hip_bf16.h>

#define B 64
#define N0 2048
#define DEG 16
#define IN_DIM 128
#define H 30
#define NH 11
#define K1 1844
#define K2 1660
#define K3 1494
#define NTOT (B * N0)        /* 131072 */
#define ETOT (NTOT * DEG)    /* 2097152 */
#define EPG (ETOT / B)       /* 32768 edges per graph, contiguous */
#define RSTRIDE 32           /* padded row stride for r, t, h */
#define ESTRIDE1 32768       /* sorted-edge capacity per graph, layers 1&3 */
#define ESTRIDE2 27648       /* layer 2: E[live]=26567, sigma~71 -> 15-sigma margin */
#define RSEG 16              /* readout segments per graph */

// ---------------------------------------------------------------------------
// Prep: fold layernorm gamma into layer-1 weights; combine rel/root weights.
// ---------------------------------------------------------------------------
__global__ __launch_bounds__(256) void k_prep(
    const float* __restrict__ ln_g, const float* __restrict__ ln_b,
    const float* __restrict__ Wrel1, const float* __restrict__ brel1, const float* __restrict__ Wroot1,
    const float* __restrict__ Wrel2, const float* __restrict__ Wroot2,
    const float* __restrict__ Wrel3, const float* __restrict__ Wroot3,
    float* __restrict__ Wc1, float* __restrict__ S1, float* __restrict__ T1,
    float* __restrict__ Wc2, float* __restrict__ Wc3)
{
    int tid = threadIdx.x;
    for (int i = tid; i < IN_DIM * 60; i += 256) {
        int j = i / 60, c = i - j * 60;
        float w = (c < H) ? Wrel1[j * H + c] : Wroot1[j * H + (c - H)];
        Wc1[i] = w * ln_g[j];
    }
    if (tid < 60) {
        int c = tid;
        float s = 0.f, tt = 0.f;
        for (int j = 0; j < IN_DIM; ++j) {
            float w = (c < H) ? Wrel1[j * H + c] : Wroot1[j * H + (c - H)];
            s += w * ln_g[j];
            tt += w * ln_b[j];
        }
        S1[c] = s;
        T1[c] = (c < H) ? tt : tt + brel1[c - H];
    }
    for (int i = tid; i < H * 60; i += 256) {
        int j = i / 60, c = i - j * 60;
        Wc2[i] = (c < H) ? Wrel2[j * H + c] : Wroot2[j * H + (c - H)];
        Wc3[i] = (c < H) ? Wrel3[j * H + c] : Wroot3[j * H + (c - H)];
    }
}

// ---------------------------------------------------------------------------
// Layer 1: fused LayerNorm + dual projection. Thread-per-row; W staged in LDS
// and read via same-address broadcast ds_read_b128 (kills the 4 GB of per-lane
// L1 W re-reads that bounded the old kernel). x prefetched one jb ahead.
// r/t written as float4 at stride 32 (pads zeroed).
// ---------------------------------------------------------------------------
__global__ __launch_bounds__(256) void k_lnproj(
    const float* __restrict__ x, const float* __restrict__ Wc,
    const float* __restrict__ S, const float* __restrict__ T,
    float* __restrict__ r, float* __restrict__ t)
{
    __shared__ float wlds[IN_DIM * 60];
    for (int i = threadIdx.x; i < IN_DIM * 60 / 4; i += 256)
        ((float4*)wlds)[i] = ((const float4*)Wc)[i];
    __syncthreads();
    int row = blockIdx.x * 256 + threadIdx.x;
    const float4* xr4 = (const float4*)(x + (size_t)row * IN_DIM);
    float acc[60];
#pragma unroll
    for (int c = 0; c < 60; ++c) acc[c] = 0.f;
    float sum = 0.f, sumsq = 0.f;
    float4 qa = xr4[0], qb = xr4[1];
    for (int jb = 0; jb < 16; ++jb) {
        float xs[8] = {qa.x, qa.y, qa.z, qa.w, qb.x, qb.y, qb.z, qb.w};
        if (jb < 15) { qa = xr4[jb * 2 + 2]; qb = xr4[jb * 2 + 3]; }
#pragma unroll
        for (int u = 0; u < 8; ++u) {
            float xv = xs[u];
            sum += xv; sumsq += xv * xv;
            const float4* w4 = (const float4*)&wlds[(jb * 8 + u) * 60];
#pragma unroll
            for (int c4 = 0; c4 < 15; ++c4) {
                float4 wv = w4[c4];
                acc[c4 * 4 + 0] += xv * wv.x;
                acc[c4 * 4 + 1] += xv * wv.y;
                acc[c4 * 4 + 2] += xv * wv.z;
                acc[c4 * 4 + 3] += xv * wv.w;
            }
        }
    }
    float mean = sum * (1.f / 128.f);
    float var = sumsq * (1.f / 128.f) - mean * mean;
    float rstd = 1.0f / sqrtf(var + 1e-5f);
    float4* rr4 = (float4*)(r + (size_t)row * RSTRIDE);
    float4* tt4 = (float4*)(t + (size_t)row * RSTRIDE);
#pragma unroll
    for (int q4 = 0; q4 < 7; ++q4) {
        float4 rv, tv;
        rv.x = rstd * (acc[q4 * 4 + 0] - mean * S[q4 * 4 + 0]) + T[q4 * 4 + 0];
        rv.y = rstd * (acc[q4 * 4 + 1] - mean * S[q4 * 4 + 1]) + T[q4 * 4 + 1];
        rv.z = rstd * (acc[q4 * 4 + 2] - mean * S[q4 * 4 + 2]) + T[q4 * 4 + 2];
        rv.w = rstd * (acc[q4 * 4 + 3] - mean * S[q4 * 4 + 3]) + T[q4 * 4 + 3];
        tv.x = rstd * (acc[30 + q4 * 4 + 0] - mean * S[30 + q4 * 4 + 0]) + T[30 + q4 * 4 + 0];
        tv.y = rstd * (acc[30 + q4 * 4 + 1] - mean * S[30 + q4 * 4 + 1]) + T[30 + q4 * 4 + 1];
        tv.z = rstd * (acc[30 + q4 * 4 + 2] - mean * S[30 + q4 * 4 + 2]) + T[30 + q4 * 4 + 2];
        tv.w = rstd * (acc[30 + q4 * 4 + 3] - mean * S[30 + q4 * 4 + 3]) + T[30 + q4 * 4 + 3];
        rr4[q4] = rv; tt4[q4] = tv;
    }
    {
        float4 rv, tv;
        rv.x = rstd * (acc[28] - mean * S[28]) + T[28];
        rv.y = rstd * (acc[29] - mean * S[29]) + T[29];
        rv.z = 0.f; rv.w = 0.f;
        tv.x = rstd * (acc[58] - mean * S[58]) + T[58];
        tv.y = rstd * (acc[59] - mean * S[59]) + T[59];
        tv.z = 0.f; tv.w = 0.f;
        rr4[7] = rv; tt4[7] = tv;
    }
}

// ---------------------------------------------------------------------------
// Pooled projection (layers 2/3): r = val*(h@Wrel); t = val*(h@Wroot) + brel.
// W (30x60) staged in LDS, broadcast reads; h-row as float4; float4 stores.
// ---------------------------------------------------------------------------
__global__ __launch_bounds__(256) void k_proj30p(
    const float* __restrict__ hbuf, const int* __restrict__ sidx,
    const float* __restrict__ score, const float* __restrict__ Wc,
    const float* __restrict__ brel, float* __restrict__ r, float* __restrict__ t,
    int n_old, int k)
{
    __shared__ float wlds[H * 60];
    for (int i = threadIdx.x; i < H * 60 / 4; i += 256)
        ((float4*)wlds)[i] = ((const float4*)Wc)[i];
    __syncthreads();
    int row = blockIdx.x * 256 + threadIdx.x;      // [0, B*k) exact grid
    int g = row / k, j = row - g * k;
    int idx = sidx[g * k + j];
    float val = score[g * n_old + idx];
    const float* hr = hbuf + (size_t)(g * n_old + idx) * RSTRIDE;
    const float4* hr4 = (const float4*)hr;
    float acc[60];
#pragma unroll
    for (int c = 0; c < 60; ++c) acc[c] = 0.f;
    auto body = [&](int m, float xv) {
        const float4* w4 = (const float4*)&wlds[m * 60];
#pragma unroll
        for (int c4 = 0; c4 < 15; ++c4) {
            float4 wv = w4[c4];
            acc[c4 * 4 + 0] += xv * wv.x;
            acc[c4 * 4 + 1] += xv * wv.y;
            acc[c4 * 4 + 2] += xv * wv.z;
            acc[c4 * 4 + 3] += xv * wv.w;
        }
    };
#pragma unroll
    for (int mb = 0; mb < 7; ++mb) {
        float4 hq = hr4[mb];
        body(mb * 4 + 0, hq.x);
        body(mb * 4 + 1, hq.y);
        body(mb * 4 + 2, hq.z);
        body(mb * 4 + 3, hq.w);
    }
    {
        float2 h2 = *(const float2*)(hr + 28);
        body(28, h2.x);
        body(29, h2.y);
    }
    float4* rr4 = (float4*)(r + (size_t)row * RSTRIDE);
    float4* tt4 = (float4*)(t + (size_t)row * RSTRIDE);
#pragma unroll
    for (int q4 = 0; q4 < 7; ++q4) {
        float4 rv, tv;
        rv.x = val * acc[q4 * 4 + 0];
        rv.y = val * acc[q4 * 4 + 1];
        rv.z = val * acc[q4 * 4 + 2];
        rv.w = val * acc[q4 * 4 + 3];
        tv.x = val * acc[30 + q4 * 4 + 0] + brel[q4 * 4 + 0];
        tv.y = val * acc[30 + q4 * 4 + 1] + brel[q4 * 4 + 1];
        tv.z = val * acc[30 + q4 * 4 + 2] + brel[q4 * 4 + 2];
        tv.w = val * acc[30 + q4 * 4 + 3] + brel[q4 * 4 + 3];
        rr4[q4] = rv; tt4[q4] = tv;
    }
    {
        float4 rv, tv;
        rv.x = val * acc[28]; rv.y = val * acc[29]; rv.z = 0.f; rv.w = 0.f;
        tv.x = val * acc[58] + brel[28];
        tv.y = val * acc[59] + brel[29];
        tv.z = 0.f; tv.w = 0.f;
        rr4[7] = rv; tt4[7] = tv;
    }
}

// ---------------------------------------------------------------------------
// Counting-sort stage 1 (layer 1): per-chunk histogram of dst + per-edge rank.
// ---------------------------------------------------------------------------
__global__ __launch_bounds__(1024) void k_hist1(
    const int* __restrict__ dst, unsigned short* __restrict__ rank,
    int* __restrict__ chunkCnt)
{
    __shared__ unsigned int cnt[2048];
    int chunk = blockIdx.x, g = chunk >> 2;
    for (int i = threadIdx.x; i < 2048; i += 1024) cnt[i] = 0;
    __syncthreads();
    int e0 = chunk * 8192;
#pragma unroll
    for (int u = 0; u < 8; ++u) {
        int e = e0 + u * 1024 + threadIdx.x;
        int d = dst[e] - g * N0;
        rank[e] = (unsigned short)atomicAdd(&cnt[d], 1u);
    }
    __syncthreads();
    for (int i = threadIdx.x; i < 2048; i += 1024) chunkCnt[chunk * 2048 + i] = cnt[i];
}

// Scatter (layer 1): plain writes, no atomics. Entry = (src_global_bits, w).
__global__ __launch_bounds__(1024) void k_scat1(
    const int* __restrict__ src, const int* __restrict__ dst, const float* __restrict__ ew,
    const unsigned short* __restrict__ rank, const int* __restrict__ chunkOff,
    float2* __restrict__ sOut)
{
    int chunk = blockIdx.x, g = chunk >> 2;
    int e0 = chunk * 8192;
#pragma unroll
    for (int u = 0; u < 8; ++u) {
        int e = e0 + u * 1024 + threadIdx.x;
        int d = dst[e] - g * N0;
        int pos = chunkOff[chunk * 2048 + d] + (int)rank[e];
        sOut[(size_t)g * ESTRIDE1 + pos] = make_float2(__int_as_float(src[e]), ew[e]);
    }
}

// ---------------------------------------------------------------------------
// Layers 2/3 sort from the ORIGINAL edge list + cumulative map (v0 -> current
// id or -1). Fully parallel & coalesced; bin = map[dst0]. 1 atomic/live edge.
// ---------------------------------------------------------------------------
__global__ __launch_bounds__(1024) void k_histE(
    const int* __restrict__ src0, const int* __restrict__ dst0,
    const int* __restrict__ mapc, unsigned short* __restrict__ rank,
    int* __restrict__ chunkCnt)
{
    __shared__ unsigned int cnt[2048];
    int chunk = blockIdx.x;
    for (int i = threadIdx.x; i < 2048; i += 1024) cnt[i] = 0;
    __syncthreads();
    int e0 = chunk * 8192;
#pragma unroll
    for (int u = 0; u < 8; ++u) {
        int e = e0 + u * 1024 + threadIdx.x;
        int dd = mapc[dst0[e]];
        int ss = mapc[src0[e]];
        if (dd >= 0 && ss >= 0)
            rank[e] = (unsigned short)atomicAdd(&cnt[dd], 1u);
    }
    __syncthreads();
    for (int i = threadIdx.x; i < 2048; i += 1024) chunkCnt[chunk * 2048 + i] = cnt[i];
}

__global__ __launch_bounds__(1024) void k_scatE(
    const int* __restrict__ src0, const int* __restrict__ dst0,
    const float* __restrict__ ew, const int* __restrict__ mapc,
    const unsigned short* __restrict__ rank, const int* __restrict__ chunkOff,
    float2* __restrict__ sOut, int k_new, int estride)
{
    int chunk = blockIdx.x, g = chunk >> 2;
    int e0 = chunk * 8192;
#pragma unroll
    for (int u = 0; u < 8; ++u) {
        int e = e0 + u * 1024 + threadIdx.x;
        int dd = mapc[dst0[e]];
        int ss = mapc[src0[e]];
        if (dd >= 0 && ss >= 0) {
            int pos = chunkOff[chunk * 2048 + dd] + (int)rank[e];
            sOut[(size_t)g * estride + pos] =
                make_float2(__int_as_float(g * k_new + ss), ew[e]);
        }
    }
}

// ---------------------------------------------------------------------------
// Per-graph scan: bin totals over 4 chunks -> exclusive scan -> runStart/Len
// + per-chunk offsets written in-place over chunkCnt.
// ---------------------------------------------------------------------------
__global__ __launch_bounds__(1024) void k_scan(
    int* __restrict__ chunkCnt, int* __restrict__ runStart, int* __restrict__ runLen)
{
    __shared__ int bufA[2048], bufB[2048];
    int g = blockIdx.x;
    int c0[2], c1[2], c2[2], tt[2];
    for (int h2 = 0; h2 < 2; ++h2) {
        int d = threadIdx.x + h2 * 1024;
        c0[h2] = chunkCnt[(g * 4 + 0) * 2048 + d];
        c1[h2] = chunkCnt[(g * 4 + 1) * 2048 + d];
        c2[h2] = chunkCnt[(g * 4 + 2) * 2048 + d];
        int c3 = chunkCnt[(g * 4 + 3) * 2048 + d];
        tt[h2] = c0[h2] + c1[h2] + c2[h2] + c3;
        bufA[d] = tt[h2];
    }
    __syncthreads();
    int* s_ = bufA; int* d_ = bufB;
    for (int off = 1; off < 2048; off <<= 1) {
        for (int h2 = 0; h2 < 2; ++h2) {
            int d = threadIdx.x + h2 * 1024;
            int v = s_[d];
            if (d >= off) v += s_[d - off];
            d_[d] = v;
        }
        __syncthreads();
        int* tmp = s_; s_ = d_; d_ = tmp;
    }
    for (int h2 = 0; h2 < 2; ++h2) {
        int d = threadIdx.x + h2 * 1024;
        int ex = s_[d] - tt[h2];
        runStart[g * 2048 + d] = ex;
        runLen[g * 2048 + d] = tt[h2];
        chunkCnt[(g * 4 + 0) * 2048 + d] = ex;
        chunkCnt[(g * 4 + 1) * 2048 + d] = ex + c0[h2];
        chunkCnt[(g * 4 + 2) * 2048 + d] = ex + c0[h2] + c1[h2];
        chunkCnt[(g * 4 + 3) * 2048 + d] = ex + c0[h2] + c1[h2] + c2[h2];
    }
}

// ---------------------------------------------------------------------------
// Run-major aggregation, ZERO atomics, fused +t/relu AND fused score:
// 32 lanes per node (lane j = feature j); shfl_xor reduce -> tanh score.
// ---------------------------------------------------------------------------
__global__ __launch_bounds__(256) void k_gather(
    const float2* __restrict__ sE, const int* __restrict__ runS, const int* __restrict__ runL,
    const float* __restrict__ rp, const float* __restrict__ t, float* __restrict__ h,
    const float* __restrict__ poolw, float* __restrict__ score,
    int n, int estride, int nblocks)
{
    int b = blockIdx.x;
    int cpx = nblocks >> 3;                 // XCD-chunked swizzle
    b = (b & 7) * cpx + (b >> 3);
    int slot = threadIdx.x >> 5, j = threadIdx.x & 31;
    int v = b * 8 + slot;
    int g = v / n;
    int local = v - g * n;
    int s0 = runS[g * 2048 + local], len = runL[g * 2048 + local];
    const float2* meta = sE + (size_t)g * estride + s0;
    float acc = 0.f;
    for (int c = 0; c < len; c += 8) {
        int lim = len - c; if (lim > 8) lim = 8;
        float2 m[8];
#pragma unroll
        for (int u = 0; u < 8; ++u) m[u] = meta[c + (u < lim ? u : 0)];
#pragma unroll
        for (int u = 0; u < 8; ++u) {
            int s = __float_as_int(m[u].x);
            float w = (u < lim) ? m[u].y : 0.f;
            acc += rp[(size_t)s * RSTRIDE + j] * w;
        }
    }
    float wj = (j < H) ? poolw[j] : 0.f;
    float hval = 0.f;
    if (j < H) {
        hval = fmaxf(acc + t[(size_t)v * RSTRIDE + j], 0.f);
        h[(size_t)v * RSTRIDE + j] = hval;
    }
    float p = hval * wj, q = wj * wj;
#pragma unroll
    for (int off = 16; off > 0; off >>= 1) {
        p += __shfl_xor(p, off, 32);
        q += __shfl_xor(q, off, 32);
    }
    if (j == 0) score[v] = tanhf(p / sqrtf(q));
}

// ---------------------------------------------------------------------------
// Top-k (desc score, asc idx; matches jax.lax.top_k tie-break) + fused
// map update: builds inv[] in LDS, writes sidx, updates cumulative map.
// ---------------------------------------------------------------------------
__global__ __launch_bounds__(1024) void k_topk_map(
    const float* __restrict__ score, int* __restrict__ sidx, int* __restrict__ mapc,
    int n, int k, int first)
{
    __shared__ unsigned long long keys[2048];
    __shared__ int inv[2048];
    int g = blockIdx.x;
    for (int i = threadIdx.x; i < 2048; i += 1024) {
        unsigned long long key = ~0ull;
        if (i < n) {
            float s = score[g * n + i];
            if (s == 0.f) s = 0.f;                 // canonicalize -0 -> +0
            unsigned u = __float_as_uint(s);
            unsigned asc = (u & 0x80000000u) ? ~u : (u | 0x80000000u);
            unsigned desc = ~asc;
            key = ((unsigned long long)desc << 32) | (unsigned)i;
        }
        keys[i] = key;
        inv[i] = -1;
    }
    __syncthreads();
    for (int kk = 2; kk <= 2048; kk <<= 1) {
        for (int jj = kk >> 1; jj > 0; jj >>= 1) {
            for (int i = threadIdx.x; i < 2048; i += 1024) {
                int ixj = i ^ jj;
                if (ixj > i) {
                    unsigned long long a = keys[i], bb = keys[ixj];
                    bool up = ((i & kk) == 0);
                    if ((a > bb) == up) { keys[i] = bb; keys[ixj] = a; }
                }
            }
            __syncthreads();
        }
    }
    for (int j = threadIdx.x; j < k; j += 1024) {
        int idx = (int)(keys[j] & 0xffffffffu);
        sidx[g * k + j] = idx;
        inv[idx] = j;
    }
    __syncthreads();
    if (first) {
        for (int v = threadIdx.x; v < N0; v += 1024)
            mapc[g * N0 + v] = inv[v];
    } else {
        for (int v = threadIdx.x; v < N0; v += 1024) {
            int m = mapc[g * N0 + v];
            mapc[g * N0 + v] = (m >= 0) ? inv[m] : -1;
        }
    }
}

// ---------------------------------------------------------------------------
// Segmented readout: grid (RSEG, B). Partial [max;sum] over a row slice.
// ---------------------------------------------------------------------------
__global__ __launch_bounds__(256) void k_rpart(
    const float* __restrict__ hbuf, const int* __restrict__ sidx,
    const float* __restrict__ score, float* __restrict__ pmax, float* __restrict__ psum,
    int n_old, int k)
{
    __shared__ float smax[8][32], ssum[8][32];
    int g = blockIdx.y, seg = blockIdx.x;
    int clen = (k + RSEG - 1) / RSEG;
    int start = seg * clen;
    int end = start + clen; if (end > k) end = k;
    int f = threadIdx.x & 31, rr = threadIdx.x >> 5;
    float mx = -INFINITY, sm = 0.f;
    if (f < H) {
        for (int j = start + rr; j < end; j += 8) {
            int idx = sidx[g * k + j];
            float val = score[g * n_old + idx];
            float v = hbuf[(size_t)(g * n_old + idx) * RSTRIDE + f] * val;
            mx = fmaxf(mx, v);
            sm += v;
        }
    }
    smax[rr][f] = mx; ssum[rr][f] = sm;
    __syncthreads();
    if (rr == 0) {
        for (int q = 1; q < 8; ++q) { mx = fmaxf(mx, smax[q][f]); sm += ssum[q][f]; }
        pmax[(g * RSEG + seg) * 32 + f] = mx;
        psum[(g * RSEG + seg) * 32 + f] = sm;
    }
}

// Finalize all 3 readouts + z = relu(x1+x2+x3). grid B, block 64.
__global__ __launch_bounds__(64) void k_zfin(
    const float* __restrict__ pm1, const float* __restrict__ ps1,
    const float* __restrict__ pm2, const float* __restrict__ ps2,
    const float* __restrict__ pm3, const float* __restrict__ ps3,
    float* __restrict__ z)
{
    int g = blockIdx.x, c = threadIdx.x;
    if (c >= 60) return;
    float v1, v2, v3;
    if (c < H) {
        float m1 = -INFINITY, m2 = -INFINITY, m3 = -INFINITY;
        for (int s = 0; s < RSEG; ++s) {
            m1 = fmaxf(m1, pm1[(g * RSEG + s) * 32 + c]);
            m2 = fmaxf(m2, pm2[(g * RSEG + s) * 32 + c]);
            m3 = fmaxf(m3, pm3[(g * RSEG + s) * 32 + c]);
        }
        v1 = m1; v2 = m2; v3 = m3;
    } else {
        int f = c - H;
        float s1 = 0.f, s2 = 0.f, s3 = 0.f;
        for (int s = 0; s < RSEG; ++s) {
            s1 += ps1[(g * RSEG + s) * 32 + f];
            s2 += ps2[(g * RSEG + s) * 32 + f];
            s3 += ps3[(g * RSEG + s) * 32 + f];
        }
        v1 = s1 / (float)K1; v2 = s2 / (float)K2; v3 = s3 / (float)K3;
    }
    z[g * 60 + c] = fmaxf(v1 + v2 + v3, 0.f);
}

// a1[h,b,o] = relu(sum_d z[b,d]*W1[h,d,o] + b1[h,o]),  o<240, d<60
__global__ __launch_bounds__(256) void k_mlp1(
    const float* __restrict__ z, const float* __restrict__ W,
    const float* __restrict__ bias, float* __restrict__ a)
{
    int hb = blockIdx.x, hh = hb >> 6, b = hb & 63;
    __shared__ float zr[60];
    if (threadIdx.x < 60) zr[threadIdx.x] = z[b * 60 + threadIdx.x];
    __syncthreads();
    int o = threadIdx.x;
    if (o < 240) {
        float acc = bias[hh * 240 + o];
        const float* Wp = W + hh * 60 * 240;
#pragma unroll
        for (int d = 0; d < 60; ++d) acc += zr[d] * Wp[d * 240 + o];
        a[(hh * B + b) * 240 + o] = fmaxf(acc, 0.f);
    }
}

// ---------------------------------------------------------------------------
// a2 GEMM: grid (11 heads x 15 col-tiles of 64). Per-head a1 tile (64x240)
// in LDS; thread = 16 rows x 1 col; one coalesced W2 load per o amortized
// over 16 FMAs via LDS broadcast. W2 read exactly once (10 MB).
// ---------------------------------------------------------------------------
__global__ __launch_bounds__(256) void k_mlp2(
    const float* __restrict__ a1, const float* __restrict__ W,
    const float* __restrict__ bias, float* __restrict__ a2)
{
    __shared__ float a1t[64 * 240];
    int hh = blockIdx.x / 15, ct = blockIdx.x % 15;
    const float4* ag = (const float4*)(a1 + (size_t)hh * B * 240);
    for (int i = threadIdx.x; i < 64 * 240 / 4; i += 256)
        ((float4*)a1t)[i] = ag[i];
    __syncthreads();
    int col = threadIdx.x & 63, rg = threadIdx.x >> 6;
    const float* Wp = W + (size_t)hh * 240 * 960 + ct * 64 + col;
    float acc[16];
#pragma unroll
    for (int i = 0; i < 16; ++i) acc[i] = 0.f;
#pragma unroll 4
    for (int o = 0; o < 240; ++o) {
        float w = Wp[(size_t)o * 960];
        const float* ar = &a1t[0];
#pragma unroll
        for (int i = 0; i < 16; ++i)
            acc[i] += w * ar[(rg * 16 + i) * 240 + o];
    }
    float bv = bias[hh * 960 + ct * 64 + col];
#pragma unroll
    for (int i = 0; i < 16; ++i)
        a2[((size_t)hh * B + rg * 16 + i) * 960 + ct * 64 + col] =
            fmaxf(acc[i] + bv, 0.f);
}

// out[h,b,q] = sum_p a2[h,b,p]*W3[h,p,q] + b3[h,q],  q<8, p<960
__global__ __launch_bounds__(64) void k_mlp3(
    const float* __restrict__ a2, const float* __restrict__ W,
    const float* __restrict__ bias, float* __restrict__ out)
{
    int hb = blockIdx.x, hh = hb >> 6, b = hb & 63;
    __shared__ float ar[960];
    __shared__ float part[64];
    for (int i = threadIdx.x; i < 960; i += 64) ar[i] = a2[(hh * B + b) * 960 + i];
    __syncthreads();
    int q = threadIdx.x & 7, c = threadIdx.x >> 3;
    const float* Wp = W + hh * 960 * 8;
    float acc = 0.f;
    for (int p = c; p < 960; p += 8) acc += ar[p] * Wp[p * 8 + q];
    part[threadIdx.x] = acc;
    __syncthreads();
    if (threadIdx.x < 8) {
        float s = bias[hh * 8 + threadIdx.x];
        for (int cc = 0; cc < 8; ++cc) s += part[cc * 8 + threadIdx.x];
        out[(hh * B + b) * 8 + threadIdx.x] = s;
    }
}

// ---------------------------------------------------------------------------
extern "C" void kernel_launch(void* const* d_in, const int* in_sizes, int n_in,
                              void* d_out, int out_size, void* d_ws, size_t ws_size,
                              hipStream_t stream)
{
    const float* x       = (const float*)d_in[0];
    const int*   eidx    = (const int*)d_in[1];
    const int*   src0    = eidx;
    const int*   dst0    = eidx + ETOT;
    const float* ew0     = (const float*)d_in[2];
    const float* ln_g    = (const float*)d_in[4];
    const float* ln_b    = (const float*)d_in[5];
    const float* W_rel1  = (const float*)d_in[6];
    const float* b_rel1  = (const float*)d_in[7];
    const float* W_root1 = (const float*)d_in[8];
    const float* W_rel2  = (const float*)d_in[9];
    const float* b_rel2  = (const float*)d_in[10];
    const float* W_root2 = (const float*)d_in[11];
    const float* W_rel3  = (const float*)d_in[12];
    const float* b_rel3  = (const float*)d_in[13];
    const float* W_root3 = (const float*)d_in[14];
    const float* pool_w1 = (const float*)d_in[15];
    const float* pool_w2 = (const float*)d_in[16];
    const float* pool_w3 = (const float*)d_in[17];
    const float* head_W1 = (const float*)d_in[18];
    const float* head_b1 = (const float*)d_in[19];
    const float* head_W2 = (const float*)d_in[20];
    const float* head_b2 = (const float*)d_in[21];
    const float* head_W3 = (const float*)d_in[22];
    const float* head_b3 = (const float*)d_in[23];

    // ---- workspace carve (~86 MB) ----
    float* ws     = (float*)d_ws;
    float* rbuf   = ws;                               // NTOT*32
    float* tbuf   = rbuf + (size_t)NTOT * RSTRIDE;    // NTOT*32 (stride 32 now)
    float* abuf   = tbuf + (size_t)NTOT * RSTRIDE;    // NTOT*32 (h, stride 32)
    float2* sA    = (float2*)(abuf + (size_t)NTOT * RSTRIDE); // B*ESTRIDE1
    float2* sB    = sA + (size_t)B * ESTRIDE1;        // B*ESTRIDE2
    float* score  = (float*)(sB + (size_t)B * ESTRIDE2);      // NTOT
    int*   sidx   = (int*)(score + NTOT);             // NTOT
    int*   mapc   = sidx + NTOT;                      // NTOT (v0 -> current id)
    int*   runSA  = mapc + NTOT;                      // B*2048 each
    int*   runLA  = runSA + B * 2048;
    int*   runSB  = runLA + B * 2048;
    int*   runLB  = runSB + B * 2048;
    float* pm1    = (float*)(runLB + B * 2048);       // B*RSEG*32 each
    float* ps1    = pm1 + B * RSEG * 32;
    float* pm2    = ps1 + B * RSEG * 32;
    float* ps2    = pm2 + B * RSEG * 32;
    float* pm3    = ps2 + B * RSEG * 32;
    float* ps3    = pm3 + B * RSEG * 32;
    float* zb     = ps3 + B * RSEG * 32;              // B*60
    float* Wc1    = zb + B * 60;                      // 128*60
    float* S1     = Wc1 + IN_DIM * 60;
    float* T1     = S1 + 60;
    float* Wc2    = T1 + 60;                          // 30*60
    float* Wc3    = Wc2 + H * 60;
    // aliases into abuf (dead h phases): chunk counters + per-edge ranks
    int* chunkBuf         = (int*)abuf;                                  // 256*2048 ints
    unsigned short* rank  = (unsigned short*)((char*)abuf + (4u << 20)); // ETOT u16
    // heads alias rbuf (dead after layer-3 gather)
    float* a1 = rbuf;
    float* a2 = a1 + NH * B * 240;

    k_prep<<<1, 256, 0, stream>>>(ln_g, ln_b, W_rel1, b_rel1, W_root1,
                                  W_rel2, W_root2, W_rel3, W_root3,
                                  Wc1, S1, T1, Wc2, Wc3);

    // ---- layer 1 ----
    k_hist1<<<256, 1024, 0, stream>>>(dst0, rank, chunkBuf);
    k_scan<<<B, 1024, 0, stream>>>(chunkBuf, runSA, runLA);
    k_scat1<<<256, 1024, 0, stream>>>(src0, dst0, ew0, rank, chunkBuf, sA);
    k_lnproj<<<NTOT / 256, 256, 0, stream>>>(x, Wc1, S1, T1, rbuf, tbuf);
    k_gather<<<NTOT / 8, 256, 0, stream>>>(sA, runSA, runLA, rbuf, tbuf, abuf,
                                           pool_w1, score, N0, ESTRIDE1, NTOT / 8);
    k_topk_map<<<B, 1024, 0, stream>>>(score, sidx, mapc, N0, K1, 1);
    k_rpart<<<dim3(RSEG, B), 256, 0, stream>>>(abuf, sidx, score, pm1, ps1, N0, K1);
    k_proj30p<<<B * K1 / 256, 256, 0, stream>>>(abuf, sidx, score, Wc2, b_rel2,
                                                rbuf, tbuf, N0, K1);

    // ---- layer 2 ----
    k_histE<<<256, 1024, 0, stream>>>(src0, dst0, mapc, rank, chunkBuf);
    k_scan<<<B, 1024, 0, stream>>>(chunkBuf, runSB, runLB);
    k_scatE<<<256, 1024, 0, stream>>>(src0, dst0, ew0, mapc, rank, chunkBuf, sB,
                                      K1, ESTRIDE2);
    k_gather<<<B * K1 / 8, 256, 0, stream>>>(sB, runSB, runLB, rbuf, tbuf, abuf,
                                             pool_w2, score, K1, ESTRIDE2, B * K1 / 8);
    k_topk_map<<<B, 1024, 0, stream>>>(score, sidx, mapc, K1, K2, 0);
    k_rpart<<<dim3(RSEG, B), 256, 0, stream>>>(abuf, sidx, score, pm2, ps2, K1, K2);
    k_proj30p<<<B * K2 / 256, 256, 0, stream>>>(abuf, sidx, score, Wc3, b_rel3,
                                                rbuf, tbuf, K1, K2);

    // ---- layer 3 ----
    k_histE<<<256, 1024, 0, stream>>>(src0, dst0, mapc, rank, chunkBuf);
    k_scan<<<B, 1024, 0, stream>>>(chunkBuf, runSA, runLA);
    k_scatE<<<256, 1024, 0, stream>>>(src0, dst0, ew0, mapc, rank, chunkBuf, sA,
                                      K2, ESTRIDE1);
    k_gather<<<B * K2 / 8, 256, 0, stream>>>(sA, runSA, runLA, rbuf, tbuf, abuf,
                                             pool_w3, score, K2, ESTRIDE1, B * K2 / 8);
    k_topk_map<<<B, 1024, 0, stream>>>(score, sidx, mapc, K2, K3, 0);
    k_rpart<<<dim3(RSEG, B), 256, 0, stream>>>(abuf, sidx, score, pm3, ps3, K2, K3);

    // ---- heads ----
    k_zfin<<<B, 64, 0, stream>>>(pm1, ps1, pm2, ps2, pm3, ps3, zb);
    k_mlp1<<<NH * B, 256, 0, stream>>>(zb, head_W1, head_b1, a1);
    k_mlp2<<<NH * 15, 256, 0, stream>>>(a1, head_W2, head_b2, a2);
    k_mlp3<<<NH * B, 64, 0, stream>>>(a2, head_W3, head_b3, (float*)d_out);
}